// Round 6
// baseline (212.500 us; speedup 1.0000x reference)
//
#include <hip/hip_runtime.h>
#include <hip/hip_bf16.h>
#include <cstdint>

#define DM   1024
#define NH   16
#define DKK  64
#define BB   4
#define SS   2048

typedef __attribute__((ext_vector_type(8)))  short short8;
typedef __attribute__((ext_vector_type(4)))  float f32x4;
typedef __attribute__((ext_vector_type(16))) float f32x16;

__device__ __forceinline__ unsigned short f2bf(float f) {
    union { float f; uint32_t u; } v; v.f = f;
    uint32_t u = v.u;
    uint32_t r = (u + 0x7FFFu + ((u >> 16) & 1u)) >> 16;   // RNE
    return (unsigned short)r;
}

// ---------------- fused fp32 -> bf16 convert (all 7 tensors) ----------------
__global__ void cvt_all(const float4* __restrict__ q, const float4* __restrict__ k,
                        const float4* __restrict__ v, const float4* __restrict__ wq,
                        const float4* __restrict__ wk, const float4* __restrict__ wv,
                        const float4* __restrict__ wo, ushort4* __restrict__ dst)
{
    const int NA = 2097152, NW = 262144;    // float4 counts
    int i = blockIdx.x * 256 + threadIdx.x;
    const float4* s;
    if (i < 3 * NA) {
        int a = i >> 21, off = i & (NA - 1);
        s = (a == 0 ? q : a == 1 ? k : v) + off;
    } else {
        int j = i - 3 * NA;
        int a = j >> 18, off = j & (NW - 1);
        s = (a == 0 ? wq : a == 1 ? wk : a == 2 ? wv : wo) + off;
    }
    float4 f = *s;
    ushort4 o;
    o.x = f2bf(f.x); o.y = f2bf(f.y); o.z = f2bf(f.z); o.w = f2bf(f.w);
    dst[i] = o;
}

// ---------------- merged QKV GEMM: z selects (A, W, bias, out, epilogue) ----------------
// C[8192][1024] = A[8192][1024] * W[1024][1024]^T + bias
// z=0: Q -> [B][H][S][64] bf16, scaled by qscale ; z=1: K -> same layout, scale 1
// z=2: V -> [B][H][64][S] bf16 (transposed)
__global__ void gemm_qkv(const unsigned short* __restrict__ Aq,
                         const unsigned short* __restrict__ Ak,
                         const unsigned short* __restrict__ Av,
                         const unsigned short* __restrict__ Wq,
                         const unsigned short* __restrict__ Wk,
                         const unsigned short* __restrict__ Wv,
                         const float* __restrict__ bq,
                         const float* __restrict__ bk,
                         const float* __restrict__ bv,
                         unsigned short* __restrict__ Qo,
                         unsigned short* __restrict__ Ko,
                         unsigned short* __restrict__ Vo,
                         const float qscale)
{
    const int z = blockIdx.z;
    const unsigned short* A  = (z == 0) ? Aq : (z == 1) ? Ak : Av;
    const unsigned short* Bw = (z == 0) ? Wq : (z == 1) ? Wk : Wv;
    const float* bias        = (z == 0) ? bq : (z == 1) ? bk : bv;

    __shared__ unsigned short lA[128 * 64];
    __shared__ unsigned short lB[128 * 64];
    const int tid = threadIdx.x;
    const int w = tid >> 6, l = tid & 63;
    const int brow = blockIdx.y * 128;
    const int bcol = blockIdx.x * 128;
    const int wr = (w >> 1) * 64, wc = (w & 1) * 64;
    const int lrow = l & 15;
    const int lk = (l >> 4) * 8;
    const int sr = l >> 3;
    const int sc = (l & 7) * 8;
    f32x4 acc[4][4] = {};

    for (int k0 = 0; k0 < 1024; k0 += 64) {
#pragma unroll
        for (int i = 0; i < 4; ++i) {
            const int chunk = w * 4 + i;
            const int r = chunk * 8 + sr;
            const unsigned short* ga = A  + (size_t)(brow + r) * 1024 + k0 + sc;
            const unsigned short* gb = Bw + (size_t)(bcol + r) * 1024 + k0 + sc;
            __builtin_amdgcn_global_load_lds((__attribute__((address_space(1))) void*)ga,
                                             (__attribute__((address_space(3))) void*)(lA + chunk * 512),
                                             16, 0, 0);
            __builtin_amdgcn_global_load_lds((__attribute__((address_space(1))) void*)gb,
                                             (__attribute__((address_space(3))) void*)(lB + chunk * 512),
                                             16, 0, 0);
        }
        asm volatile("s_waitcnt vmcnt(0)" ::: "memory");
        __syncthreads();
#pragma unroll
        for (int kk = 0; kk < 2; ++kk) {
            short8 af[4], bfr[4];
#pragma unroll
            for (int m = 0; m < 4; ++m)
                af[m] = *(const short8*)(lA + (wr + m * 16 + lrow) * 64 + kk * 32 + lk);
#pragma unroll
            for (int n = 0; n < 4; ++n)
                bfr[n] = *(const short8*)(lB + (wc + n * 16 + lrow) * 64 + kk * 32 + lk);
#pragma unroll
            for (int m = 0; m < 4; ++m)
#pragma unroll
                for (int n = 0; n < 4; ++n)
                    acc[m][n] = __builtin_amdgcn_mfma_f32_16x16x32_bf16(af[m], bfr[n], acc[m][n], 0, 0, 0);
        }
        __syncthreads();
    }

    const float ascale = (z == 0) ? qscale : 1.0f;
#pragma unroll
    for (int m = 0; m < 4; ++m) {
#pragma unroll
        for (int n = 0; n < 4; ++n) {
            const int i0 = brow + wr + m * 16 + (l >> 4) * 4;
            const int j  = bcol + wc + n * 16 + lrow;
            const float bj = bias[j];
            const int hh = j >> 6, d = j & 63;
            if (z < 2) {
                unsigned short* Cb = (z == 0) ? Qo : Ko;
#pragma unroll
                for (int t = 0; t < 4; ++t) {
                    const int i = i0 + t;
                    const int b = i >> 11, s = i & 2047;
                    Cb[(((size_t)(b * NH + hh) * SS) + s) * DKK + d] = f2bf((acc[m][n][t] + bj) * ascale);
                }
            } else {   // V^T
                const int b = i0 >> 11, s0 = i0 & 2047;
                ushort4 pk;
                pk.x = f2bf(acc[m][n][0] + bj);
                pk.y = f2bf(acc[m][n][1] + bj);
                pk.z = f2bf(acc[m][n][2] + bj);
                pk.w = f2bf(acc[m][n][3] + bj);
                *(ushort4*)(Vo + (((size_t)(b * NH + hh) * DKK) + d) * SS + s0) = pk;
            }
        }
    }
}

// ---------------- final projection GEMM: fp32 out row-major ----------------
__global__ void gemm_out(const unsigned short* __restrict__ A,
                         const unsigned short* __restrict__ Bw,
                         const float* __restrict__ bias,
                         float* __restrict__ Cout)
{
    __shared__ unsigned short lA[128 * 64];
    __shared__ unsigned short lB[128 * 64];
    const int tid = threadIdx.x;
    const int w = tid >> 6, l = tid & 63;
    const int brow = blockIdx.y * 128;
    const int bcol = blockIdx.x * 128;
    const int wr = (w >> 1) * 64, wc = (w & 1) * 64;
    const int lrow = l & 15;
    const int lk = (l >> 4) * 8;
    const int sr = l >> 3;
    const int sc = (l & 7) * 8;
    f32x4 acc[4][4] = {};

    for (int k0 = 0; k0 < 1024; k0 += 64) {
#pragma unroll
        for (int i = 0; i < 4; ++i) {
            const int chunk = w * 4 + i;
            const int r = chunk * 8 + sr;
            const unsigned short* ga = A  + (size_t)(brow + r) * 1024 + k0 + sc;
            const unsigned short* gb = Bw + (size_t)(bcol + r) * 1024 + k0 + sc;
            __builtin_amdgcn_global_load_lds((__attribute__((address_space(1))) void*)ga,
                                             (__attribute__((address_space(3))) void*)(lA + chunk * 512),
                                             16, 0, 0);
            __builtin_amdgcn_global_load_lds((__attribute__((address_space(1))) void*)gb,
                                             (__attribute__((address_space(3))) void*)(lB + chunk * 512),
                                             16, 0, 0);
        }
        asm volatile("s_waitcnt vmcnt(0)" ::: "memory");
        __syncthreads();
#pragma unroll
        for (int kk = 0; kk < 2; ++kk) {
            short8 af[4], bfr[4];
#pragma unroll
            for (int m = 0; m < 4; ++m)
                af[m] = *(const short8*)(lA + (wr + m * 16 + lrow) * 64 + kk * 32 + lk);
#pragma unroll
            for (int n = 0; n < 4; ++n)
                bfr[n] = *(const short8*)(lB + (wc + n * 16 + lrow) * 64 + kk * 32 + lk);
#pragma unroll
            for (int m = 0; m < 4; ++m)
#pragma unroll
                for (int n = 0; n < 4; ++n)
                    acc[m][n] = __builtin_amdgcn_mfma_f32_16x16x32_bf16(af[m], bfr[n], acc[m][n], 0, 0, 0);
        }
        __syncthreads();
    }

#pragma unroll
    for (int m = 0; m < 4; ++m) {
#pragma unroll
        for (int n = 0; n < 4; ++n) {
            const int i0 = brow + wr + m * 16 + (l >> 4) * 4;
            const int j  = bcol + wc + n * 16 + lrow;
            const float bj = bias[j];
#pragma unroll
            for (int t = 0; t < 4; ++t)
                Cout[(size_t)(i0 + t) * DM + j] = acc[m][n][t] + bj;
        }
    }
}

// ---------------- causal flash attention, swapped-QK^T 32x32, constant-work blocks ----------
// Q,K: [B*H][S][64] bf16 (Q pre-scaled by log2e/8) ; Vt: [B*H][64][S] bf16 ; AO: [B][S][H*64]
// Block = (head, pair p): processes q-chunk p AND chunk 31-p (64 rows each, 2 waves x 32 rows)
// sequentially -> staged tiles per block = (2p+2)+(2(31-p)+2) = 68 CONSTANT (no tail, any
// dispatch order). K/V tiles (32 kv) staged via regs -> XOR-swizzled ds_write, double-buffered.
__global__ __launch_bounds__(128) void attn_kernel(
        const unsigned short* __restrict__ Q,
        const unsigned short* __restrict__ K,
        const unsigned short* __restrict__ Vt,
        unsigned short* __restrict__ AO)
{
    const int flat = blockIdx.y * 16 + blockIdx.x;   // grid (16,64) -> 1024 blocks
    const int r8 = flat & 7;
    const int rest = flat >> 3;                      // 0..127
    const int bh = r8 * 8 + (rest & 7);              // 8 heads per XCD residue -> K/V L2-shared
    const int pair = rest >> 3;                      // 0..15
    const int tid = threadIdx.x;
    const int w = tid >> 6, l = tid & 63;
    const int ln = l & 31, h = l >> 5;

    // K tile: 32 rows x 128B (row = kv, col byte = d*2)
    // V tile: 32 rows x 128B (row r: bytes 0..63 = d=r; bytes 64..127 = d=r+32)
    __shared__ __align__(16) char lK[2][4096];
    __shared__ __align__(16) char lV[2][4096];

    const unsigned short* Kp = K  + (size_t)bh * SS * DKK;
    const unsigned short* Vp = Vt + (size_t)bh * DKK * SS;

    // staging (128 thr): each thread 2 K pieces + 2 V pieces (16B each), linear global src,
    // XOR-swizzled LDS write address (m214 pattern)
    const int srow = tid >> 2, sc4 = tid & 3;
    const int sw0 = srow * 128 + ((sc4 * 16)      ^ ((srow & 7) << 4));
    const int sw1 = srow * 128 + ((sc4 * 16 + 64) ^ ((srow & 7) << 4));
    const unsigned short* ksrc0 = Kp + srow * DKK + sc4 * 8;            // + t*2048
    const unsigned short* ksrc1 = ksrc0 + 32;
    const unsigned short* vsrc0 = Vp + (size_t)srow * SS + sc4 * 8;     // + t*32
    const unsigned short* vsrc1 = Vp + (size_t)(srow + 32) * SS + sc4 * 8;

    // ds_read byte offsets (tile-invariant), same XOR swizzle
    int ka[4], va[4];
#pragma unroll
    for (int ks = 0; ks < 4; ++ks)
        ka[ks] = ln * 128 + ((ks * 32 + h * 16) ^ ((ln & 7) << 4));
#pragma unroll
    for (int c = 0; c < 4; ++c)
        va[c] = ln * 128 + ((c * 32 + h * 16) ^ ((ln & 7) << 4));

    short8 ones;
#pragma unroll
    for (int i = 0; i < 8; ++i) ones[i] = (short)0x3F80;   // bf16 1.0

    const int bb = bh >> 4, hh = bh & 15;

    for (int half = 0; half < 2; ++half) {
        const int qc = half ? (31 - pair) : pair;    // complementary chunks
        const int q0w = qc * 64 + w * 32;
        const unsigned short* Qp = Q + ((size_t)bh * SS + q0w) * DKK;

        short8 qf[4];
#pragma unroll
        for (int ks = 0; ks < 4; ++ks)
            qf[ks] = *(const short8*)(Qp + (size_t)ln * DKK + ks * 16 + h * 8);

        f32x16 o0 = {}, o1 = {}, ol = {};
        const int Twave = 2 * qc + w;    // last tile this wave computes (diag)
        const int NT = 2 * qc + 2;       // staged tiles

        // prologue: stage tile 0
        short8 k0 = *(const short8*)(ksrc0);
        short8 k1 = *(const short8*)(ksrc1);
        short8 v0 = *(const short8*)(vsrc0);
        short8 v1 = *(const short8*)(vsrc1);
        *(short8*)(&lK[0][sw0]) = k0;
        *(short8*)(&lK[0][sw1]) = k1;
        *(short8*)(&lV[0][sw0]) = v0;
        *(short8*)(&lV[0][sw1]) = v1;
        __syncthreads();

        int buf = 0;
        for (int t = 0; t < NT; ++t) {
            const bool pf = (t + 1 < NT);
            if (pf) {   // issue next-tile loads early; latency hides under compute
                k0 = *(const short8*)(ksrc0 + (size_t)(t + 1) * 2048);
                k1 = *(const short8*)(ksrc1 + (size_t)(t + 1) * 2048);
                v0 = *(const short8*)(vsrc0 + (size_t)(t + 1) * 32);
                v1 = *(const short8*)(vsrc1 + (size_t)(t + 1) * 32);
            }
            if (t <= Twave) {
                const char* kb = lK[buf];
                const char* vb = lV[buf];
                short8 kf[4];
#pragma unroll
                for (int ks = 0; ks < 4; ++ks) kf[ks] = *(const short8*)(kb + ka[ks]);

                f32x16 s = {};
                __builtin_amdgcn_s_setprio(1);
#pragma unroll
                for (int ks = 0; ks < 4; ++ks)
                    s = __builtin_amdgcn_mfma_f32_32x32x16_bf16(kf[ks], qf[ks], s, 0, 0, 0);
                __builtin_amdgcn_s_setprio(0);

                const bool diag = (t == Twave);
                float p[16];
#pragma unroll
                for (int r = 0; r < 16; ++r) {
                    float e;
                    asm("v_exp_f32 %0, %1" : "=v"(e) : "v"(s[r]));   // 2^s (Q pre-scaled)
                    if (diag) {
                        const int crow = (r & 3) + 8 * (r >> 2) + 4 * h;  // kv offset
                        e = (crow > ln) ? 0.f : e;
                    }
                    p[r] = e;
                }

                uint32_t pk[8];
#pragma unroll
                for (int i = 0; i < 8; ++i) {
                    uint32_t d;
                    asm("v_cvt_pk_bf16_f32 %0, %1, %2" : "=v"(d) : "v"(p[2 * i]), "v"(p[2 * i + 1]));
                    pk[i] = d;
                }
                asm("v_permlane32_swap_b32 %0, %1" : "+v"(pk[0]), "+v"(pk[2]));
                asm("v_permlane32_swap_b32 %0, %1" : "+v"(pk[1]), "+v"(pk[3]));
                asm("v_permlane32_swap_b32 %0, %1" : "+v"(pk[4]), "+v"(pk[6]));
                asm("v_permlane32_swap_b32 %0, %1" : "+v"(pk[5]), "+v"(pk[7]));

                union Ux { uint32_t u[4]; short8 s8; } pa0, pa1;
                pa0.u[0] = pk[0]; pa0.u[1] = pk[1]; pa0.u[2] = pk[2]; pa0.u[3] = pk[3];
                pa1.u[0] = pk[4]; pa1.u[1] = pk[5]; pa1.u[2] = pk[6]; pa1.u[3] = pk[7];

                short8 vf00 = *(const short8*)(vb + va[0]);
                short8 vf10 = *(const short8*)(vb + va[1]);
                short8 vf01 = *(const short8*)(vb + va[2]);
                short8 vf11 = *(const short8*)(vb + va[3]);

                __builtin_amdgcn_s_setprio(1);
                o0 = __builtin_amdgcn_mfma_f32_32x32x16_bf16(pa0.s8, vf00, o0, 0, 0, 0);
                o0 = __builtin_amdgcn_mfma_f32_32x32x16_bf16(pa1.s8, vf10, o0, 0, 0, 0);
                o1 = __builtin_amdgcn_mfma_f32_32x32x16_bf16(pa0.s8, vf01, o1, 0, 0, 0);
                o1 = __builtin_amdgcn_mfma_f32_32x32x16_bf16(pa1.s8, vf11, o1, 0, 0, 0);
                ol = __builtin_amdgcn_mfma_f32_32x32x16_bf16(pa0.s8, ones, ol, 0, 0, 0);
                ol = __builtin_amdgcn_mfma_f32_32x32x16_bf16(pa1.s8, ones, ol, 0, 0, 0);
                __builtin_amdgcn_s_setprio(0);
            }
            if (pf) {   // write-late into the other buffer; next barrier publishes it
                *(short8*)(&lK[buf ^ 1][sw0]) = k0;
                *(short8*)(&lK[buf ^ 1][sw1]) = k1;
                *(short8*)(&lV[buf ^ 1][sw0]) = v0;
                *(short8*)(&lV[buf ^ 1][sw1]) = v1;
            }
            __syncthreads();
            buf ^= 1;
        }

#pragma unroll
        for (int r = 0; r < 16; ++r) {
            const int crow = (r & 3) + 8 * (r >> 2) + 4 * h;
            const float rl = __builtin_amdgcn_rcpf(ol[r]);   // lsum for this q-row
            const size_t row = (size_t)(bb * SS + q0w + crow) * DM + hh * DKK;
            AO[row + ln]      = f2bf(o0[r] * rl);
            AO[row + 32 + ln] = f2bf(o1[r] * rl);
        }
    }
}

extern "C" void kernel_launch(void* const* d_in, const int* in_sizes, int n_in,
                              void* d_out, int out_size, void* d_ws, size_t ws_size,
                              hipStream_t stream)
{
    const float* query  = (const float*)d_in[0];
    const float* key_in = (const float*)d_in[1];
    const float* value  = (const float*)d_in[2];
    const float* Wq = (const float*)d_in[3];
    const float* bq = (const float*)d_in[4];
    const float* Wk = (const float*)d_in[5];
    const float* bk = (const float*)d_in[6];
    const float* Wv = (const float*)d_in[7];
    const float* bv = (const float*)d_in[8];
    const float* Wo = (const float*)d_in[9];
    const float* bo = (const float*)d_in[10];

    const size_t NACT = (size_t)BB * SS * DM;   // 8388608
    const size_t NWT  = (size_t)DM * DM;        // 1048576

    unsigned short* ws  = (unsigned short*)d_ws;
    unsigned short* qin = ws;
    unsigned short* kin = qin + NACT;
    unsigned short* vin = kin + NACT;
    unsigned short* wqb = vin + NACT;
    unsigned short* wkb = wqb + NWT;
    unsigned short* wvb = wkb + NWT;
    unsigned short* wob = wvb + NWT;
    unsigned short* Qb  = wob + NWT;
    unsigned short* Kb  = Qb + NACT;
    unsigned short* Vtb = Kb + NACT;
    unsigned short* AOb = Vtb + NACT;

    const int n4 = (int)(3 * (NACT / 4) + 4 * (NWT / 4));   // 7340032
    cvt_all<<<n4 / 256, 256, 0, stream>>>((const float4*)query, (const float4*)key_in,
                                          (const float4*)value, (const float4*)Wq,
                                          (const float4*)Wk, (const float4*)Wv,
                                          (const float4*)Wo, (ushort4*)ws);

    const float QSCALE = 0.125f * 1.44269504088896f;   // 1/sqrt(64) * log2(e)
    dim3 gq(DM / 128, (BB * SS) / 128, 3);   // (8, 64, 3)
    gemm_qkv<<<gq, 256, 0, stream>>>(qin, kin, vin, wqb, wkb, wvb,
                                     bq, bk, bv, Qb, Kb, Vtb, QSCALE);

    attn_kernel<<<dim3(16, 64), 128, 0, stream>>>(Qb, Kb, Vtb, AOb);

    dim3 gg(DM / 128, (BB * SS) / 128);   // (8, 64)
    gemm_out<<<gg, 256, 0, stream>>>(AOb, wob, bo, (float*)d_out);
}

// Round 7
// 190.322 us; speedup vs baseline: 1.1165x; 1.1165x over previous
//
#include <hip/hip_runtime.h>
#include <hip/hip_bf16.h>
#include <cstdint>

#define DM   1024
#define NH   16
#define DKK  64
#define BB   4
#define SS   2048

typedef __attribute__((ext_vector_type(8)))  short short8;
typedef __attribute__((ext_vector_type(4)))  float f32x4;
typedef __attribute__((ext_vector_type(16))) float f32x16;

__device__ __forceinline__ unsigned short f2bf(float f) {
    union { float f; uint32_t u; } v; v.f = f;
    uint32_t u = v.u;
    uint32_t r = (u + 0x7FFFu + ((u >> 16) & 1u)) >> 16;   // RNE
    return (unsigned short)r;
}

// ---------------- fused fp32 -> bf16 convert (all 7 tensors) ----------------
__global__ void cvt_all(const float4* __restrict__ q, const float4* __restrict__ k,
                        const float4* __restrict__ v, const float4* __restrict__ wq,
                        const float4* __restrict__ wk, const float4* __restrict__ wv,
                        const float4* __restrict__ wo, ushort4* __restrict__ dst)
{
    const int NA = 2097152, NW = 262144;    // float4 counts
    int i = blockIdx.x * 256 + threadIdx.x;
    const float4* s;
    if (i < 3 * NA) {
        int a = i >> 21, off = i & (NA - 1);
        s = (a == 0 ? q : a == 1 ? k : v) + off;
    } else {
        int j = i - 3 * NA;
        int a = j >> 18, off = j & (NW - 1);
        s = (a == 0 ? wq : a == 1 ? wk : a == 2 ? wv : wo) + off;
    }
    float4 f = *s;
    ushort4 o;
    o.x = f2bf(f.x); o.y = f2bf(f.y); o.z = f2bf(f.z); o.w = f2bf(f.w);
    dst[i] = o;
}

// ---------------- merged QKV GEMM: z selects (A, W, bias, out, epilogue) ----------------
__global__ void gemm_qkv(const unsigned short* __restrict__ Aq,
                         const unsigned short* __restrict__ Ak,
                         const unsigned short* __restrict__ Av,
                         const unsigned short* __restrict__ Wq,
                         const unsigned short* __restrict__ Wk,
                         const unsigned short* __restrict__ Wv,
                         const float* __restrict__ bq,
                         const float* __restrict__ bk,
                         const float* __restrict__ bv,
                         unsigned short* __restrict__ Qo,
                         unsigned short* __restrict__ Ko,
                         unsigned short* __restrict__ Vo,
                         const float qscale)
{
    const int z = blockIdx.z;
    const unsigned short* A  = (z == 0) ? Aq : (z == 1) ? Ak : Av;
    const unsigned short* Bw = (z == 0) ? Wq : (z == 1) ? Wk : Wv;
    const float* bias        = (z == 0) ? bq : (z == 1) ? bk : bv;

    __shared__ unsigned short lA[128 * 64];
    __shared__ unsigned short lB[128 * 64];
    const int tid = threadIdx.x;
    const int w = tid >> 6, l = tid & 63;
    const int brow = blockIdx.y * 128;
    const int bcol = blockIdx.x * 128;
    const int wr = (w >> 1) * 64, wc = (w & 1) * 64;
    const int lrow = l & 15;
    const int lk = (l >> 4) * 8;
    const int sr = l >> 3;
    const int sc = (l & 7) * 8;
    f32x4 acc[4][4] = {};

    for (int k0 = 0; k0 < 1024; k0 += 64) {
#pragma unroll
        for (int i = 0; i < 4; ++i) {
            const int chunk = w * 4 + i;
            const int r = chunk * 8 + sr;
            const unsigned short* ga = A  + (size_t)(brow + r) * 1024 + k0 + sc;
            const unsigned short* gb = Bw + (size_t)(bcol + r) * 1024 + k0 + sc;
            __builtin_amdgcn_global_load_lds((__attribute__((address_space(1))) void*)ga,
                                             (__attribute__((address_space(3))) void*)(lA + chunk * 512),
                                             16, 0, 0);
            __builtin_amdgcn_global_load_lds((__attribute__((address_space(1))) void*)gb,
                                             (__attribute__((address_space(3))) void*)(lB + chunk * 512),
                                             16, 0, 0);
        }
        asm volatile("s_waitcnt vmcnt(0)" ::: "memory");
        __syncthreads();
#pragma unroll
        for (int kk = 0; kk < 2; ++kk) {
            short8 af[4], bfr[4];
#pragma unroll
            for (int m = 0; m < 4; ++m)
                af[m] = *(const short8*)(lA + (wr + m * 16 + lrow) * 64 + kk * 32 + lk);
#pragma unroll
            for (int n = 0; n < 4; ++n)
                bfr[n] = *(const short8*)(lB + (wc + n * 16 + lrow) * 64 + kk * 32 + lk);
#pragma unroll
            for (int m = 0; m < 4; ++m)
#pragma unroll
                for (int n = 0; n < 4; ++n)
                    acc[m][n] = __builtin_amdgcn_mfma_f32_16x16x32_bf16(af[m], bfr[n], acc[m][n], 0, 0, 0);
        }
        __syncthreads();
    }

    const float ascale = (z == 0) ? qscale : 1.0f;
#pragma unroll
    for (int m = 0; m < 4; ++m) {
#pragma unroll
        for (int n = 0; n < 4; ++n) {
            const int i0 = brow + wr + m * 16 + (l >> 4) * 4;
            const int j  = bcol + wc + n * 16 + lrow;
            const float bj = bias[j];
            const int hh = j >> 6, d = j & 63;
            if (z < 2) {
                unsigned short* Cb = (z == 0) ? Qo : Ko;
#pragma unroll
                for (int t = 0; t < 4; ++t) {
                    const int i = i0 + t;
                    const int b = i >> 11, s = i & 2047;
                    Cb[(((size_t)(b * NH + hh) * SS) + s) * DKK + d] = f2bf((acc[m][n][t] + bj) * ascale);
                }
            } else {   // V^T
                const int b = i0 >> 11, s0 = i0 & 2047;
                ushort4 pk;
                pk.x = f2bf(acc[m][n][0] + bj);
                pk.y = f2bf(acc[m][n][1] + bj);
                pk.z = f2bf(acc[m][n][2] + bj);
                pk.w = f2bf(acc[m][n][3] + bj);
                *(ushort4*)(Vo + (((size_t)(b * NH + hh) * DKK) + d) * SS + s0) = pk;
            }
        }
    }
}

// ---------------- final projection GEMM: fp32 out row-major ----------------
__global__ void gemm_out(const unsigned short* __restrict__ A,
                         const unsigned short* __restrict__ Bw,
                         const float* __restrict__ bias,
                         float* __restrict__ Cout)
{
    __shared__ unsigned short lA[128 * 64];
    __shared__ unsigned short lB[128 * 64];
    const int tid = threadIdx.x;
    const int w = tid >> 6, l = tid & 63;
    const int brow = blockIdx.y * 128;
    const int bcol = blockIdx.x * 128;
    const int wr = (w >> 1) * 64, wc = (w & 1) * 64;
    const int lrow = l & 15;
    const int lk = (l >> 4) * 8;
    const int sr = l >> 3;
    const int sc = (l & 7) * 8;
    f32x4 acc[4][4] = {};

    for (int k0 = 0; k0 < 1024; k0 += 64) {
#pragma unroll
        for (int i = 0; i < 4; ++i) {
            const int chunk = w * 4 + i;
            const int r = chunk * 8 + sr;
            const unsigned short* ga = A  + (size_t)(brow + r) * 1024 + k0 + sc;
            const unsigned short* gb = Bw + (size_t)(bcol + r) * 1024 + k0 + sc;
            __builtin_amdgcn_global_load_lds((__attribute__((address_space(1))) void*)ga,
                                             (__attribute__((address_space(3))) void*)(lA + chunk * 512),
                                             16, 0, 0);
            __builtin_amdgcn_global_load_lds((__attribute__((address_space(1))) void*)gb,
                                             (__attribute__((address_space(3))) void*)(lB + chunk * 512),
                                             16, 0, 0);
        }
        asm volatile("s_waitcnt vmcnt(0)" ::: "memory");
        __syncthreads();
#pragma unroll
        for (int kk = 0; kk < 2; ++kk) {
            short8 af[4], bfr[4];
#pragma unroll
            for (int m = 0; m < 4; ++m)
                af[m] = *(const short8*)(lA + (wr + m * 16 + lrow) * 64 + kk * 32 + lk);
#pragma unroll
            for (int n = 0; n < 4; ++n)
                bfr[n] = *(const short8*)(lB + (wc + n * 16 + lrow) * 64 + kk * 32 + lk);
#pragma unroll
            for (int m = 0; m < 4; ++m)
#pragma unroll
                for (int n = 0; n < 4; ++n)
                    acc[m][n] = __builtin_amdgcn_mfma_f32_16x16x32_bf16(af[m], bfr[n], acc[m][n], 0, 0, 0);
        }
        __syncthreads();
    }

#pragma unroll
    for (int m = 0; m < 4; ++m) {
#pragma unroll
        for (int n = 0; n < 4; ++n) {
            const int i0 = brow + wr + m * 16 + (l >> 4) * 4;
            const int j  = bcol + wc + n * 16 + lrow;
            const float bj = bias[j];
#pragma unroll
            for (int t = 0; t < 4; ++t)
                Cout[(size_t)(i0 + t) * DM + j] = acc[m][n][t] + bj;
        }
    }
}

// ---------------- causal flash attention, swapped-QK^T 32x32, reg-staged LDS K/V ----------------
// Round-5 structure (4-wave blocks, 8-thr/row staging, depth-2 pipeline) with:
//  - LPT dispatch: qchunk = 15 - (flat>>6) so longest blocks dispatch FIRST (kills the tail)
//  - no ones-MFMA: per-lane scalar lsum (saves 16 acc VGPRs, -2 MFMA/stage)
__global__ __launch_bounds__(256) void attn_kernel(
        const unsigned short* __restrict__ Q,
        const unsigned short* __restrict__ K,
        const unsigned short* __restrict__ Vt,
        unsigned short* __restrict__ AO)
{
    const int flat = blockIdx.y * 16 + blockIdx.x;      // grid (16, 64)
    const int r8 = flat & 7, k8 = flat >> 3;
    const int bh = r8 * 8 + (k8 & 7);                   // 8 heads per XCD-residue (L2 share)
    const int qchunk = 15 - (k8 >> 3);                  // LPT: long blocks first
    const int tid = threadIdx.x;
    const int w = tid >> 6, l = tid & 63;
    const int ln = l & 31, h = l >> 5;
    const int qb = qchunk * 128;
    const int q0w = qb + w * 32;

    // K tile: 32 rows x 128B (row = kv, col byte = d*2)
    // V tile: 32 rows x 128B (row r: bytes 0..63 = d=r; bytes 64..127 = d=r+32)
    __shared__ __align__(16) char lK[2][4096];
    __shared__ __align__(16) char lV[2][4096];

    const unsigned short* Qp = Q  + ((size_t)bh * SS + q0w) * DKK;
    const unsigned short* Kp = K  + (size_t)bh * SS * DKK;
    const unsigned short* Vp = Vt + (size_t)bh * DKK * SS;

    // staging: LINEAR global src, swizzled LDS write addr (m214 pattern); 8 thr/row -> all 32 banks
    const int srow = tid >> 3, scb = tid & 7;
    const int swb = srow * 128 + ((scb * 16) ^ ((srow & 7) << 4));
    const unsigned short* ksrc = Kp + srow * DKK + scb * 8;            // + t*2048
    const int vd = (scb < 4) ? srow : (srow + 32);
    const unsigned short* vsrc = Vp + (size_t)vd * SS + (scb & 3) * 8; // + t*32

    // ds_read byte offsets (tile-invariant), same XOR swizzle
    int ka[4], va[4];
#pragma unroll
    for (int ks = 0; ks < 4; ++ks)
        ka[ks] = ln * 128 + ((ks * 32 + h * 16) ^ ((ln & 7) << 4));
#pragma unroll
    for (int c = 0; c < 4; ++c)   // c = dblk*2 + ks2
        va[c] = ln * 128 + ((c * 32 + h * 16) ^ ((ln & 7) << 4));

    // Q fragment (B operand): lane holds q = q0w+ln, d = ks*16 + h*8 + j
    short8 qf[4];
#pragma unroll
    for (int ks = 0; ks < 4; ++ks)
        qf[ks] = *(const short8*)(Qp + (size_t)ln * DKK + ks * 16 + h * 8);

    f32x16 o0 = {}, o1 = {};
    float lsum = 0.f;

    const int Tc = qb / 32;       // tiles common to all waves
    const int NT = Tc + 4;        // staged tiles per block (>=4)

    auto compute = [&](int t, int buf) {
        const char* kb = lK[buf];
        const char* vb = lV[buf];
        short8 kf[4];
#pragma unroll
        for (int ks = 0; ks < 4; ++ks) kf[ks] = *(const short8*)(kb + ka[ks]);

        f32x16 s = {};
        __builtin_amdgcn_s_setprio(1);
#pragma unroll
        for (int ks = 0; ks < 4; ++ks)
            s = __builtin_amdgcn_mfma_f32_32x32x16_bf16(kf[ks], qf[ks], s, 0, 0, 0);
        __builtin_amdgcn_s_setprio(0);

        const bool diag = (t == Tc + w);
#pragma unroll
        for (int r = 0; r < 16; ++r) {
            float e;
            asm("v_exp_f32 %0, %1" : "=v"(e) : "v"(s[r]));   // 2^s (Q pre-scaled)
            if (diag) {
                const int crow = (r & 3) + 8 * (r >> 2) + 4 * h;  // kv offset
                e = (crow > ln) ? 0.f : e;
            }
            s[r] = e;           // in-place: p over s
            lsum += e;
        }

        uint32_t pk[8];
#pragma unroll
        for (int i = 0; i < 8; ++i) {
            uint32_t d;
            asm("v_cvt_pk_bf16_f32 %0, %1, %2" : "=v"(d) : "v"(s[2 * i]), "v"(s[2 * i + 1]));
            pk[i] = d;
        }
        asm("v_permlane32_swap_b32 %0, %1" : "+v"(pk[0]), "+v"(pk[2]));
        asm("v_permlane32_swap_b32 %0, %1" : "+v"(pk[1]), "+v"(pk[3]));
        asm("v_permlane32_swap_b32 %0, %1" : "+v"(pk[4]), "+v"(pk[6]));
        asm("v_permlane32_swap_b32 %0, %1" : "+v"(pk[5]), "+v"(pk[7]));

        union Ux { uint32_t u[4]; short8 s8; } pa0, pa1;
        pa0.u[0] = pk[0]; pa0.u[1] = pk[1]; pa0.u[2] = pk[2]; pa0.u[3] = pk[3];
        pa1.u[0] = pk[4]; pa1.u[1] = pk[5]; pa1.u[2] = pk[6]; pa1.u[3] = pk[7];

        short8 vf00 = *(const short8*)(vb + va[0]);
        short8 vf10 = *(const short8*)(vb + va[1]);
        short8 vf01 = *(const short8*)(vb + va[2]);
        short8 vf11 = *(const short8*)(vb + va[3]);

        __builtin_amdgcn_s_setprio(1);
        o0 = __builtin_amdgcn_mfma_f32_32x32x16_bf16(pa0.s8, vf00, o0, 0, 0, 0);
        o0 = __builtin_amdgcn_mfma_f32_32x32x16_bf16(pa1.s8, vf10, o0, 0, 0, 0);
        o1 = __builtin_amdgcn_mfma_f32_32x32x16_bf16(pa0.s8, vf01, o1, 0, 0, 0);
        o1 = __builtin_amdgcn_mfma_f32_32x32x16_bf16(pa1.s8, vf11, o1, 0, 0, 0);
        __builtin_amdgcn_s_setprio(0);
    };

    // prologue: tile0 -> LDS[0]; A <- tile1
    short8 kA = *(const short8*)(ksrc);
    short8 vA = *(const short8*)(vsrc);
    *(short8*)(&lK[0][swb]) = kA;
    *(short8*)(&lV[0][swb]) = vA;
    kA = *(const short8*)(ksrc + 2048);
    vA = *(const short8*)(vsrc + 32);
    short8 kB = {}, vB = {};
    __syncthreads();

    int t = 0, buf = 0;
    for (;;) {
        // step with next=A, far=B
        if (t + 2 < NT) {
            kB = *(const short8*)(ksrc + (size_t)(t + 2) * 2048);
            vB = *(const short8*)(vsrc + (size_t)(t + 2) * 32);
        }
        if (t <= Tc + w) compute(t, buf);
        if (t + 1 < NT) {
            *(short8*)(&lK[buf ^ 1][swb]) = kA;
            *(short8*)(&lV[buf ^ 1][swb]) = vA;
        }
        __syncthreads();
        buf ^= 1;
        if (++t == NT) break;

        // step with next=B, far=A
        if (t + 2 < NT) {
            kA = *(const short8*)(ksrc + (size_t)(t + 2) * 2048);
            vA = *(const short8*)(vsrc + (size_t)(t + 2) * 32);
        }
        if (t <= Tc + w) compute(t, buf);
        if (t + 1 < NT) {
            *(short8*)(&lK[buf ^ 1][swb]) = kB;
            *(short8*)(&lV[buf ^ 1][swb]) = vB;
        }
        __syncthreads();
        buf ^= 1;
        if (++t == NT) break;
    }

    lsum += __shfl_xor(lsum, 32, 64);    // merge partner kv-half (q = ln now complete)
    const float rcp = 1.0f / lsum;

    const int bb = bh >> 4, hh = bh & 15;
#pragma unroll
    for (int r = 0; r < 16; ++r) {
        const int crow = (r & 3) + 8 * (r >> 2) + 4 * h;
        const float rl = __shfl(rcp, crow, 64);          // 1/lsum for q-row crow
        const size_t row = (size_t)(bb * SS + q0w + crow) * DM + hh * DKK;
        AO[row + ln]      = f2bf(o0[r] * rl);
        AO[row + 32 + ln] = f2bf(o1[r] * rl);
    }
}

extern "C" void kernel_launch(void* const* d_in, const int* in_sizes, int n_in,
                              void* d_out, int out_size, void* d_ws, size_t ws_size,
                              hipStream_t stream)
{
    const float* query  = (const float*)d_in[0];
    const float* key_in = (const float*)d_in[1];
    const float* value  = (const float*)d_in[2];
    const float* Wq = (const float*)d_in[3];
    const float* bq = (const float*)d_in[4];
    const float* Wk = (const float*)d_in[5];
    const float* bk = (const float*)d_in[6];
    const float* Wv = (const float*)d_in[7];
    const float* bv = (const float*)d_in[8];
    const float* Wo = (const float*)d_in[9];
    const float* bo = (const float*)d_in[10];

    const size_t NACT = (size_t)BB * SS * DM;   // 8388608
    const size_t NWT  = (size_t)DM * DM;        // 1048576

    unsigned short* ws  = (unsigned short*)d_ws;
    unsigned short* qin = ws;
    unsigned short* kin = qin + NACT;
    unsigned short* vin = kin + NACT;
    unsigned short* wqb = vin + NACT;
    unsigned short* wkb = wqb + NWT;
    unsigned short* wvb = wkb + NWT;
    unsigned short* wob = wvb + NWT;
    unsigned short* Qb  = wob + NWT;
    unsigned short* Kb  = Qb + NACT;
    unsigned short* Vtb = Kb + NACT;
    unsigned short* AOb = Vtb + NACT;

    const int n4 = (int)(3 * (NACT / 4) + 4 * (NWT / 4));   // 7340032
    cvt_all<<<n4 / 256, 256, 0, stream>>>((const float4*)query, (const float4*)key_in,
                                          (const float4*)value, (const float4*)Wq,
                                          (const float4*)Wk, (const float4*)Wv,
                                          (const float4*)Wo, (ushort4*)ws);

    const float QSCALE = 0.125f * 1.44269504088896f;   // 1/sqrt(64) * log2(e)
    dim3 gq(DM / 128, (BB * SS) / 128, 3);   // (8, 64, 3)
    gemm_qkv<<<gq, 256, 0, stream>>>(qin, kin, vin, wqb, wkb, wvb,
                                     bq, bk, bv, Qb, Kb, Vtb, QSCALE);

    attn_kernel<<<dim3(16, 64), 256, 0, stream>>>(Qb, Kb, Vtb, AOb);

    dim3 gg(DM / 128, (BB * SS) / 128);   // (8, 64)
    gemm_out<<<gg, 256, 0, stream>>>(AOb, wob, bo, (float*)d_out);
}

// Round 8
// 175.218 us; speedup vs baseline: 1.2128x; 1.0862x over previous
//
#include <hip/hip_runtime.h>
#include <hip/hip_bf16.h>
#include <cstdint>

#define DM   1024
#define NH   16
#define DKK  64
#define BB   4
#define SS   2048

typedef __attribute__((ext_vector_type(8)))  short short8;
typedef __attribute__((ext_vector_type(4)))  float f32x4;
typedef __attribute__((ext_vector_type(16))) float f32x16;

__device__ __forceinline__ unsigned short f2bf(float f) {
    union { float f; uint32_t u; } v; v.f = f;
    uint32_t u = v.u;
    uint32_t r = (u + 0x7FFFu + ((u >> 16) & 1u)) >> 16;   // RNE
    return (unsigned short)r;
}

// ---------------- fp32 -> bf16 convert (4 weight matrices only) ----------------
__global__ void cvt_w(const float4* __restrict__ wq, const float4* __restrict__ wk,
                      const float4* __restrict__ wv, const float4* __restrict__ wo,
                      ushort4* __restrict__ dst)
{
    const int NW = 262144;    // float4 per weight
    int i = blockIdx.x * 256 + threadIdx.x;
    int a = i >> 18, off = i & (NW - 1);
    const float4* s = (a == 0 ? wq : a == 1 ? wk : a == 2 ? wv : wo) + off;
    float4 f = *s;
    ushort4 o;
    o.x = f2bf(f.x); o.y = f2bf(f.y); o.z = f2bf(f.z); o.w = f2bf(f.w);
    dst[i] = o;
}

// ---------------- merged QKV GEMM, fused A fp32->bf16, XCD-swizzled ----------------
// C[8192][1024] = A_fp32[8192][1024] * W_bf16[1024][1024]^T + bias
// z=0: Q -> [B][H][S][64] bf16 scaled ; z=1: K same ; z=2: V -> [B][H][64][S] (transposed)
__global__ void gemm_qkv(const float* __restrict__ Aq,
                         const float* __restrict__ Ak,
                         const float* __restrict__ Av,
                         const unsigned short* __restrict__ Wq,
                         const unsigned short* __restrict__ Wk,
                         const unsigned short* __restrict__ Wv,
                         const float* __restrict__ bq,
                         const float* __restrict__ bk,
                         const float* __restrict__ bv,
                         unsigned short* __restrict__ Qo,
                         unsigned short* __restrict__ Ko,
                         unsigned short* __restrict__ Vo,
                         const float qscale)
{
    // bijective XCD swizzle: 1536 blocks, 192/XCD contiguous wids -> A-panel+W reuse in L2
    const int orig = blockIdx.z * 512 + blockIdx.y * 8 + blockIdx.x;
    const int wid  = (orig & 7) * 192 + (orig >> 3);
    const int z    = wid >> 9;
    const int rem  = wid & 511;
    const int brow = (rem >> 3) * 128;
    const int bcol = (rem & 7) * 128;

    const float* A           = (z == 0) ? Aq : (z == 1) ? Ak : Av;
    const unsigned short* Bw = (z == 0) ? Wq : (z == 1) ? Wk : Wv;
    const float* bias        = (z == 0) ? bq : (z == 1) ? bk : bv;

    __shared__ unsigned short lA[128 * 64];
    __shared__ unsigned short lB[128 * 64];
    const int tid = threadIdx.x;
    const int w = tid >> 6, l = tid & 63;
    const int wr = (w >> 1) * 64, wc = (w & 1) * 64;
    const int lrow = l & 15;
    const int lk = (l >> 4) * 8;
    const int sr = l >> 3;          // row within 8-row chunk
    const int sc = (l & 7) * 8;     // elem col
    f32x4 acc[4][4] = {};

    for (int k0 = 0; k0 < 1024; k0 += 64) {
        // B: async global->LDS (bf16 weights)
#pragma unroll
        for (int i = 0; i < 4; ++i) {
            const int chunk = w * 4 + i;
            const int r = chunk * 8 + sr;
            const unsigned short* gb = Bw + (size_t)(bcol + r) * 1024 + k0 + sc;
            __builtin_amdgcn_global_load_lds((__attribute__((address_space(1))) void*)gb,
                                             (__attribute__((address_space(3))) void*)(lB + chunk * 512),
                                             16, 0, 0);
        }
        // A: reg-staged fp32 -> bf16 -> LDS (same linear layout as gload_lds)
#pragma unroll
        for (int i = 0; i < 4; ++i) {
            const int chunk = w * 4 + i;
            const int r = chunk * 8 + sr;
            const float* ga = A + (size_t)(brow + r) * 1024 + k0 + sc;
            float4 f0 = *(const float4*)(ga);
            float4 f1 = *(const float4*)(ga + 4);
            union { uint32_t u[4]; short8 s8; } c;
            asm("v_cvt_pk_bf16_f32 %0, %1, %2" : "=v"(c.u[0]) : "v"(f0.x), "v"(f0.y));
            asm("v_cvt_pk_bf16_f32 %0, %1, %2" : "=v"(c.u[1]) : "v"(f0.z), "v"(f0.w));
            asm("v_cvt_pk_bf16_f32 %0, %1, %2" : "=v"(c.u[2]) : "v"(f1.x), "v"(f1.y));
            asm("v_cvt_pk_bf16_f32 %0, %1, %2" : "=v"(c.u[3]) : "v"(f1.z), "v"(f1.w));
            *(short8*)((char*)lA + chunk * 1024 + sr * 128 + sc * 2) = c.s8;
        }
        asm volatile("s_waitcnt vmcnt(0)" ::: "memory");
        __syncthreads();
#pragma unroll
        for (int kk = 0; kk < 2; ++kk) {
            short8 af[4], bfr[4];
#pragma unroll
            for (int m = 0; m < 4; ++m)
                af[m] = *(const short8*)(lA + (wr + m * 16 + lrow) * 64 + kk * 32 + lk);
#pragma unroll
            for (int n = 0; n < 4; ++n)
                bfr[n] = *(const short8*)(lB + (wc + n * 16 + lrow) * 64 + kk * 32 + lk);
#pragma unroll
            for (int m = 0; m < 4; ++m)
#pragma unroll
                for (int n = 0; n < 4; ++n)
                    acc[m][n] = __builtin_amdgcn_mfma_f32_16x16x32_bf16(af[m], bfr[n], acc[m][n], 0, 0, 0);
        }
        __syncthreads();
    }

    const float ascale = (z == 0) ? qscale : 1.0f;
#pragma unroll
    for (int m = 0; m < 4; ++m) {
#pragma unroll
        for (int n = 0; n < 4; ++n) {
            const int i0 = brow + wr + m * 16 + (l >> 4) * 4;
            const int j  = bcol + wc + n * 16 + lrow;
            const float bj = bias[j];
            const int hh = j >> 6, d = j & 63;
            if (z < 2) {
                unsigned short* Cb = (z == 0) ? Qo : Ko;
#pragma unroll
                for (int t = 0; t < 4; ++t) {
                    const int i = i0 + t;
                    const int b = i >> 11, s = i & 2047;
                    Cb[(((size_t)(b * NH + hh) * SS) + s) * DKK + d] = f2bf((acc[m][n][t] + bj) * ascale);
                }
            } else {   // V^T
                const int b = i0 >> 11, s0 = i0 & 2047;
                ushort4 pk;
                pk.x = f2bf(acc[m][n][0] + bj);
                pk.y = f2bf(acc[m][n][1] + bj);
                pk.z = f2bf(acc[m][n][2] + bj);
                pk.w = f2bf(acc[m][n][3] + bj);
                *(ushort4*)(Vo + (((size_t)(b * NH + hh) * DKK) + d) * SS + s0) = pk;
            }
        }
    }
}

// ---------------- final projection GEMM: fp32 out row-major, XCD-swizzled ----------------
__global__ void gemm_out(const unsigned short* __restrict__ A,
                         const unsigned short* __restrict__ Bw,
                         const float* __restrict__ bias,
                         float* __restrict__ Cout)
{
    const int orig = blockIdx.y * 8 + blockIdx.x;
    const int wid  = (orig & 7) * 64 + (orig >> 3);
    const int brow = (wid >> 3) * 128;
    const int bcol = (wid & 7) * 128;

    __shared__ unsigned short lA[128 * 64];
    __shared__ unsigned short lB[128 * 64];
    const int tid = threadIdx.x;
    const int w = tid >> 6, l = tid & 63;
    const int wr = (w >> 1) * 64, wc = (w & 1) * 64;
    const int lrow = l & 15;
    const int lk = (l >> 4) * 8;
    const int sr = l >> 3;
    const int sc = (l & 7) * 8;
    f32x4 acc[4][4] = {};

    for (int k0 = 0; k0 < 1024; k0 += 64) {
#pragma unroll
        for (int i = 0; i < 4; ++i) {
            const int chunk = w * 4 + i;
            const int r = chunk * 8 + sr;
            const unsigned short* ga = A  + (size_t)(brow + r) * 1024 + k0 + sc;
            const unsigned short* gb = Bw + (size_t)(bcol + r) * 1024 + k0 + sc;
            __builtin_amdgcn_global_load_lds((__attribute__((address_space(1))) void*)ga,
                                             (__attribute__((address_space(3))) void*)(lA + chunk * 512),
                                             16, 0, 0);
            __builtin_amdgcn_global_load_lds((__attribute__((address_space(1))) void*)gb,
                                             (__attribute__((address_space(3))) void*)(lB + chunk * 512),
                                             16, 0, 0);
        }
        asm volatile("s_waitcnt vmcnt(0)" ::: "memory");
        __syncthreads();
#pragma unroll
        for (int kk = 0; kk < 2; ++kk) {
            short8 af[4], bfr[4];
#pragma unroll
            for (int m = 0; m < 4; ++m)
                af[m] = *(const short8*)(lA + (wr + m * 16 + lrow) * 64 + kk * 32 + lk);
#pragma unroll
            for (int n = 0; n < 4; ++n)
                bfr[n] = *(const short8*)(lB + (wc + n * 16 + lrow) * 64 + kk * 32 + lk);
#pragma unroll
            for (int m = 0; m < 4; ++m)
#pragma unroll
                for (int n = 0; n < 4; ++n)
                    acc[m][n] = __builtin_amdgcn_mfma_f32_16x16x32_bf16(af[m], bfr[n], acc[m][n], 0, 0, 0);
        }
        __syncthreads();
    }

#pragma unroll
    for (int m = 0; m < 4; ++m) {
#pragma unroll
        for (int n = 0; n < 4; ++n) {
            const int i0 = brow + wr + m * 16 + (l >> 4) * 4;
            const int j  = bcol + wc + n * 16 + lrow;
            const float bj = bias[j];
#pragma unroll
            for (int t = 0; t < 4; ++t)
                Cout[(size_t)(i0 + t) * DM + j] = acc[m][n][t] + bj;
        }
    }
}

// ---------------- causal flash attention (round-7, unchanged) ----------------
__global__ __launch_bounds__(256) void attn_kernel(
        const unsigned short* __restrict__ Q,
        const unsigned short* __restrict__ K,
        const unsigned short* __restrict__ Vt,
        unsigned short* __restrict__ AO)
{
    const int flat = blockIdx.y * 16 + blockIdx.x;      // grid (16, 64)
    const int r8 = flat & 7, k8 = flat >> 3;
    const int bh = r8 * 8 + (k8 & 7);                   // 8 heads per XCD-residue (L2 share)
    const int qchunk = 15 - (k8 >> 3);                  // LPT: long blocks first
    const int tid = threadIdx.x;
    const int w = tid >> 6, l = tid & 63;
    const int ln = l & 31, h = l >> 5;
    const int qb = qchunk * 128;
    const int q0w = qb + w * 32;

    __shared__ __align__(16) char lK[2][4096];
    __shared__ __align__(16) char lV[2][4096];

    const unsigned short* Qp = Q  + ((size_t)bh * SS + q0w) * DKK;
    const unsigned short* Kp = K  + (size_t)bh * SS * DKK;
    const unsigned short* Vp = Vt + (size_t)bh * DKK * SS;

    const int srow = tid >> 3, scb = tid & 7;
    const int swb = srow * 128 + ((scb * 16) ^ ((srow & 7) << 4));
    const unsigned short* ksrc = Kp + srow * DKK + scb * 8;            // + t*2048
    const int vd = (scb < 4) ? srow : (srow + 32);
    const unsigned short* vsrc = Vp + (size_t)vd * SS + (scb & 3) * 8; // + t*32

    int ka[4], va[4];
#pragma unroll
    for (int ks = 0; ks < 4; ++ks)
        ka[ks] = ln * 128 + ((ks * 32 + h * 16) ^ ((ln & 7) << 4));
#pragma unroll
    for (int c = 0; c < 4; ++c)
        va[c] = ln * 128 + ((c * 32 + h * 16) ^ ((ln & 7) << 4));

    short8 qf[4];
#pragma unroll
    for (int ks = 0; ks < 4; ++ks)
        qf[ks] = *(const short8*)(Qp + (size_t)ln * DKK + ks * 16 + h * 8);

    f32x16 o0 = {}, o1 = {};
    float lsum = 0.f;

    const int Tc = qb / 32;
    const int NT = Tc + 4;

    auto compute = [&](int t, int buf) {
        const char* kb = lK[buf];
        const char* vb = lV[buf];
        short8 kf[4];
#pragma unroll
        for (int ks = 0; ks < 4; ++ks) kf[ks] = *(const short8*)(kb + ka[ks]);

        f32x16 s = {};
        __builtin_amdgcn_s_setprio(1);
#pragma unroll
        for (int ks = 0; ks < 4; ++ks)
            s = __builtin_amdgcn_mfma_f32_32x32x16_bf16(kf[ks], qf[ks], s, 0, 0, 0);
        __builtin_amdgcn_s_setprio(0);

        const bool diag = (t == Tc + w);
#pragma unroll
        for (int r = 0; r < 16; ++r) {
            float e;
            asm("v_exp_f32 %0, %1" : "=v"(e) : "v"(s[r]));   // 2^s (Q pre-scaled)
            if (diag) {
                const int crow = (r & 3) + 8 * (r >> 2) + 4 * h;
                e = (crow > ln) ? 0.f : e;
            }
            s[r] = e;
            lsum += e;
        }

        uint32_t pk[8];
#pragma unroll
        for (int i = 0; i < 8; ++i) {
            uint32_t d;
            asm("v_cvt_pk_bf16_f32 %0, %1, %2" : "=v"(d) : "v"(s[2 * i]), "v"(s[2 * i + 1]));
            pk[i] = d;
        }
        asm("v_permlane32_swap_b32 %0, %1" : "+v"(pk[0]), "+v"(pk[2]));
        asm("v_permlane32_swap_b32 %0, %1" : "+v"(pk[1]), "+v"(pk[3]));
        asm("v_permlane32_swap_b32 %0, %1" : "+v"(pk[4]), "+v"(pk[6]));
        asm("v_permlane32_swap_b32 %0, %1" : "+v"(pk[5]), "+v"(pk[7]));

        union Ux { uint32_t u[4]; short8 s8; } pa0, pa1;
        pa0.u[0] = pk[0]; pa0.u[1] = pk[1]; pa0.u[2] = pk[2]; pa0.u[3] = pk[3];
        pa1.u[0] = pk[4]; pa1.u[1] = pk[5]; pa1.u[2] = pk[6]; pa1.u[3] = pk[7];

        short8 vf00 = *(const short8*)(vb + va[0]);
        short8 vf10 = *(const short8*)(vb + va[1]);
        short8 vf01 = *(const short8*)(vb + va[2]);
        short8 vf11 = *(const short8*)(vb + va[3]);

        __builtin_amdgcn_s_setprio(1);
        o0 = __builtin_amdgcn_mfma_f32_32x32x16_bf16(pa0.s8, vf00, o0, 0, 0, 0);
        o0 = __builtin_amdgcn_mfma_f32_32x32x16_bf16(pa1.s8, vf10, o0, 0, 0, 0);
        o1 = __builtin_amdgcn_mfma_f32_32x32x16_bf16(pa0.s8, vf01, o1, 0, 0, 0);
        o1 = __builtin_amdgcn_mfma_f32_32x32x16_bf16(pa1.s8, vf11, o1, 0, 0, 0);
        __builtin_amdgcn_s_setprio(0);
    };

    short8 kA = *(const short8*)(ksrc);
    short8 vA = *(const short8*)(vsrc);
    *(short8*)(&lK[0][swb]) = kA;
    *(short8*)(&lV[0][swb]) = vA;
    kA = *(const short8*)(ksrc + 2048);
    vA = *(const short8*)(vsrc + 32);
    short8 kB = {}, vB = {};
    __syncthreads();

    int t = 0, buf = 0;
    for (;;) {
        if (t + 2 < NT) {
            kB = *(const short8*)(ksrc + (size_t)(t + 2) * 2048);
            vB = *(const short8*)(vsrc + (size_t)(t + 2) * 32);
        }
        if (t <= Tc + w) compute(t, buf);
        if (t + 1 < NT) {
            *(short8*)(&lK[buf ^ 1][swb]) = kA;
            *(short8*)(&lV[buf ^ 1][swb]) = vA;
        }
        __syncthreads();
        buf ^= 1;
        if (++t == NT) break;

        if (t + 2 < NT) {
            kA = *(const short8*)(ksrc + (size_t)(t + 2) * 2048);
            vA = *(const short8*)(vsrc + (size_t)(t + 2) * 32);
        }
        if (t <= Tc + w) compute(t, buf);
        if (t + 1 < NT) {
            *(short8*)(&lK[buf ^ 1][swb]) = kB;
            *(short8*)(&lV[buf ^ 1][swb]) = vB;
        }
        __syncthreads();
        buf ^= 1;
        if (++t == NT) break;
    }

    lsum += __shfl_xor(lsum, 32, 64);
    const float rcp = 1.0f / lsum;

    const int bb = bh >> 4, hh = bh & 15;
#pragma unroll
    for (int r = 0; r < 16; ++r) {
        const int crow = (r & 3) + 8 * (r >> 2) + 4 * h;
        const float rl = __shfl(rcp, crow, 64);
        const size_t row = (size_t)(bb * SS + q0w + crow) * DM + hh * DKK;
        AO[row + ln]      = f2bf(o0[r] * rl);
        AO[row + 32 + ln] = f2bf(o1[r] * rl);
    }
}

extern "C" void kernel_launch(void* const* d_in, const int* in_sizes, int n_in,
                              void* d_out, int out_size, void* d_ws, size_t ws_size,
                              hipStream_t stream)
{
    const float* query  = (const float*)d_in[0];
    const float* key_in = (const float*)d_in[1];
    const float* value  = (const float*)d_in[2];
    const float* Wq = (const float*)d_in[3];
    const float* bq = (const float*)d_in[4];
    const float* Wk = (const float*)d_in[5];
    const float* bk = (const float*)d_in[6];
    const float* Wv = (const float*)d_in[7];
    const float* bv = (const float*)d_in[8];
    const float* Wo = (const float*)d_in[9];
    const float* bo = (const float*)d_in[10];

    const size_t NACT = (size_t)BB * SS * DM;   // 8388608
    const size_t NWT  = (size_t)DM * DM;        // 1048576

    unsigned short* ws  = (unsigned short*)d_ws;
    unsigned short* wqb = ws;
    unsigned short* wkb = wqb + NWT;
    unsigned short* wvb = wkb + NWT;
    unsigned short* wob = wvb + NWT;
    unsigned short* Qb  = wob + NWT;
    unsigned short* Kb  = Qb + NACT;
    unsigned short* Vtb = Kb + NACT;
    unsigned short* AOb = Vtb + NACT;

    const int n4 = (int)(4 * (NWT / 4));   // 1048576 float4s
    cvt_w<<<n4 / 256, 256, 0, stream>>>((const float4*)Wq, (const float4*)Wk,
                                        (const float4*)Wv, (const float4*)Wo,
                                        (ushort4*)ws);

    const float QSCALE = 0.125f * 1.44269504088896f;   // 1/sqrt(64) * log2(e)
    dim3 gq(DM / 128, (BB * SS) / 128, 3);   // (8, 64, 3)
    gemm_qkv<<<gq, 256, 0, stream>>>(query, key_in, value, wqb, wkb, wvb,
                                     bq, bk, bv, Qb, Kb, Vtb, QSCALE);

    attn_kernel<<<dim3(16, 64), 256, 0, stream>>>(Qb, Kb, Vtb, AOb);

    dim3 gg(DM / 128, (BB * SS) / 128);   // (8, 64)
    gemm_out<<<gg, 256, 0, stream>>>(AOb, wob, bo, (float*)d_out);
}

// Round 9
// 166.640 us; speedup vs baseline: 1.2752x; 1.0515x over previous
//
#include <hip/hip_runtime.h>
#include <hip/hip_bf16.h>
#include <cstdint>

#define DM   1024
#define NH   16
#define DKK  64
#define BB   4
#define SS   2048

typedef __attribute__((ext_vector_type(8)))  short short8;
typedef __attribute__((ext_vector_type(4)))  float f32x4;
typedef __attribute__((ext_vector_type(16))) float f32x16;

__device__ __forceinline__ unsigned short f2bf(float f) {
    union { float f; uint32_t u; } v; v.f = f;
    uint32_t u = v.u;
    uint32_t r = (u + 0x7FFFu + ((u >> 16) & 1u)) >> 16;   // RNE
    return (unsigned short)r;
}

#define GLL(src, dst) __builtin_amdgcn_global_load_lds(                      \
        (__attribute__((address_space(1))) void*)(src),                      \
        (__attribute__((address_space(3))) void*)(dst), 16, 0, 0)

// ---------------- fp32 -> bf16 convert + PRE-SWIZZLE (4 weight matrices) ----------------
// Output W_sw[j][kb*8..] = W[j][kbs*8..] with kbs = (kb&~7) | ((kb^j)&7)  (16B-block XOR
// within each 64-col k-tile) so that linear global_load_lds yields the T2-swizzled LDS tile.
__global__ void cvt_w(const float* __restrict__ wq, const float* __restrict__ wk,
                      const float* __restrict__ wv, const float* __restrict__ wo,
                      unsigned short* __restrict__ dst)
{
    int i = blockIdx.x * 256 + threadIdx.x;      // 16B-block id: 4 * 1024 * 128
    int a = i >> 17;
    int r = i & 131071;
    int j = r >> 7, kb = r & 127;
    int kbs = (kb & ~7) | ((kb ^ j) & 7);
    const float* s = (a == 0 ? wq : a == 1 ? wk : a == 2 ? wv : wo) + (size_t)j * 1024 + kbs * 8;
    float4 f0 = *(const float4*)(s);
    float4 f1 = *(const float4*)(s + 4);
    union { uint32_t u[4]; short8 s8; } c;
    asm("v_cvt_pk_bf16_f32 %0, %1, %2" : "=v"(c.u[0]) : "v"(f0.x), "v"(f0.y));
    asm("v_cvt_pk_bf16_f32 %0, %1, %2" : "=v"(c.u[1]) : "v"(f0.z), "v"(f0.w));
    asm("v_cvt_pk_bf16_f32 %0, %1, %2" : "=v"(c.u[2]) : "v"(f1.x), "v"(f1.y));
    asm("v_cvt_pk_bf16_f32 %0, %1, %2" : "=v"(c.u[3]) : "v"(f1.z), "v"(f1.w));
    *(short8*)(dst + ((size_t)a << 20) + (size_t)j * 1024 + kb * 8) = c.s8;
}

// ---------------- merged QKV GEMM: fused A cvt, T2 swizzle, T3/T4 pipeline ----------------
// C[8192][1024] = A_fp32[8192][1024] * W_bf16sw[1024][1024]^T + bias
// z=0: Q -> [B][H][S][64] bf16 scaled ; z=1: K same ; z=2: V -> [B][H][64][S] (transposed)
__global__ __launch_bounds__(256) void gemm_qkv(
        const float* __restrict__ Aq, const float* __restrict__ Ak, const float* __restrict__ Av,
        const unsigned short* __restrict__ Wq, const unsigned short* __restrict__ Wk,
        const unsigned short* __restrict__ Wv,
        const float* __restrict__ bq, const float* __restrict__ bk, const float* __restrict__ bv,
        unsigned short* __restrict__ Qo, unsigned short* __restrict__ Ko,
        unsigned short* __restrict__ Vo, const float qscale)
{
    // bijective XCD swizzle: 1536 blocks -> 192 contiguous wids per XCD (L2 panel reuse)
    const int orig = blockIdx.z * 512 + blockIdx.y * 8 + blockIdx.x;
    const int wid  = (orig & 7) * 192 + (orig >> 3);
    const int z    = wid >> 9;
    const int rem  = wid & 511;
    const int brow = (rem >> 3) * 128;
    const int bcol = (rem & 7) * 128;

    const float* A           = (z == 0) ? Aq : (z == 1) ? Ak : Av;
    const unsigned short* Bw = (z == 0) ? Wq : (z == 1) ? Wk : Wv;
    const float* bias        = (z == 0) ? bq : (z == 1) ? bk : bv;

    __shared__ __align__(16) unsigned short lA[128 * 64];
    __shared__ __align__(16) unsigned short lB[2][128 * 64];

    const int tid = threadIdx.x;
    const int w = tid >> 6, l = tid & 63;
    const int wr = (w >> 1) * 64, wc = (w & 1) * 64;
    const int lrow = l & 15;
    const int hi = l >> 4;            // 0..3
    const int sr = l >> 3, scb = l & 7;

    // A staging: global fp32 (linear) -> regs -> swizzled ds_write
    const float* aga[4];
    int awb[4];
#pragma unroll
    for (int i = 0; i < 4; ++i) {
        const int chunk = w * 4 + i;
        const int r = chunk * 8 + sr;
        aga[i] = A + (size_t)(brow + r) * 1024 + scb * 8;
        awb[i] = chunk * 1024 + sr * 128 + ((scb ^ sr) << 4);
    }

    f32x4 areg[4][2];
    f32x4 acc[4][4] = {};

    // prologue: issue B(0) -> lB[0]; load A(0) regs
#pragma unroll
    for (int i = 0; i < 4; ++i) {
        const int chunk = w * 4 + i;
        const int r = chunk * 8 + sr;
        GLL(Bw + (size_t)(bcol + r) * 1024 + scb * 8, lB[0] + chunk * 512);
    }
#pragma unroll
    for (int i = 0; i < 4; ++i) {
        areg[i][0] = *(const f32x4*)(aga[i]);
        areg[i][1] = *(const f32x4*)(aga[i] + 4);
    }

    for (int t = 0; t < 16; ++t) {
        // 1. cvt A(t) regs -> swizzled LDS write (auto-waits the A loads; B(t) may stay in flight)
#pragma unroll
        for (int i = 0; i < 4; ++i) {
            union { uint32_t u[4]; short8 s8; } c;
            asm("v_cvt_pk_bf16_f32 %0, %1, %2" : "=v"(c.u[0]) : "v"(areg[i][0][0]), "v"(areg[i][0][1]));
            asm("v_cvt_pk_bf16_f32 %0, %1, %2" : "=v"(c.u[1]) : "v"(areg[i][0][2]), "v"(areg[i][0][3]));
            asm("v_cvt_pk_bf16_f32 %0, %1, %2" : "=v"(c.u[2]) : "v"(areg[i][1][0]), "v"(areg[i][1][1]));
            asm("v_cvt_pk_bf16_f32 %0, %1, %2" : "=v"(c.u[3]) : "v"(areg[i][1][2]), "v"(areg[i][1][3]));
            *(short8*)((char*)lA + awb[i]) = c.s8;
        }
        if (t < 15) {
            const int k0n = (t + 1) * 64;
            // 2. prefetch A(t+1) regs (safe: cvt already consumed areg)
#pragma unroll
            for (int i = 0; i < 4; ++i) {
                areg[i][0] = *(const f32x4*)(aga[i] + k0n);
                areg[i][1] = *(const f32x4*)(aga[i] + k0n + 4);
            }
            // 3. prefetch B(t+1) -> other LDS buffer
#pragma unroll
            for (int i = 0; i < 4; ++i) {
                const int chunk = w * 4 + i;
                const int r = chunk * 8 + sr;
                GLL(Bw + (size_t)(bcol + r) * 1024 + k0n + scb * 8, lB[(t + 1) & 1] + chunk * 512);
            }
            // 4. drain B(t) (oldest 4 of 16) + ds_writes; keep A(t+1)+B(t+1) in flight
            asm volatile("s_waitcnt vmcnt(12) lgkmcnt(0)" ::: "memory");
        } else {
            asm volatile("s_waitcnt vmcnt(0) lgkmcnt(0)" ::: "memory");
        }
        __builtin_amdgcn_s_barrier();
        // 5. MFMA on lA, lB[t&1] (swizzled reads: 2-way conflict, free)
        const unsigned short* lb = lB[t & 1];
        __builtin_amdgcn_s_setprio(1);
#pragma unroll
        for (int kk = 0; kk < 2; ++kk) {
            short8 af[4], bf[4];
#pragma unroll
            for (int m = 0; m < 4; ++m) {
                const int row = wr + m * 16 + lrow;
                const int pb = (kk * 4 + hi) ^ (row & 7);
                af[m] = *(const short8*)((const char*)lA + row * 128 + (pb << 4));
            }
#pragma unroll
            for (int n = 0; n < 4; ++n) {
                const int row = wc + n * 16 + lrow;
                const int pb = (kk * 4 + hi) ^ (row & 7);
                bf[n] = *(const short8*)((const char*)lb + row * 128 + (pb << 4));
            }
#pragma unroll
            for (int m = 0; m < 4; ++m)
#pragma unroll
                for (int n = 0; n < 4; ++n)
                    acc[m][n] = __builtin_amdgcn_mfma_f32_16x16x32_bf16(af[m], bf[n], acc[m][n], 0, 0, 0);
        }
        __builtin_amdgcn_s_setprio(0);
        asm volatile("" ::: "memory");
        __builtin_amdgcn_s_barrier();   // protect lA overwrite next iter
        asm volatile("" ::: "memory");
    }

    const float ascale = (z == 0) ? qscale : 1.0f;
#pragma unroll
    for (int m = 0; m < 4; ++m) {
#pragma unroll
        for (int n = 0; n < 4; ++n) {
            const int i0 = brow + wr + m * 16 + (l >> 4) * 4;
            const int j  = bcol + wc + n * 16 + lrow;
            const float bj = bias[j];
            const int hh = j >> 6, d = j & 63;
            if (z < 2) {
                unsigned short* Cb = (z == 0) ? Qo : Ko;
#pragma unroll
                for (int t = 0; t < 4; ++t) {
                    const int i = i0 + t;
                    const int b = i >> 11, s = i & 2047;
                    Cb[(((size_t)(b * NH + hh) * SS) + s) * DKK + d] = f2bf((acc[m][n][t] + bj) * ascale);
                }
            } else {   // V^T
                const int b = i0 >> 11, s0 = i0 & 2047;
                ushort4 pk;
                pk.x = f2bf(acc[m][n][0] + bj);
                pk.y = f2bf(acc[m][n][1] + bj);
                pk.z = f2bf(acc[m][n][2] + bj);
                pk.w = f2bf(acc[m][n][3] + bj);
                *(ushort4*)(Vo + (((size_t)(b * NH + hh) * DKK) + d) * SS + s0) = pk;
            }
        }
    }
}

// ---------------- final projection GEMM: fp32 out, XCD-swizzled, swizzled-W reads ----------
__global__ void gemm_out(const unsigned short* __restrict__ A,
                         const unsigned short* __restrict__ Bw,
                         const float* __restrict__ bias,
                         float* __restrict__ Cout)
{
    const int orig = blockIdx.y * 8 + blockIdx.x;
    const int wid  = (orig & 7) * 64 + (orig >> 3);
    const int brow = (wid >> 3) * 128;
    const int bcol = (wid & 7) * 128;

    __shared__ unsigned short lA[128 * 64];
    __shared__ unsigned short lB[128 * 64];
    const int tid = threadIdx.x;
    const int w = tid >> 6, l = tid & 63;
    const int wr = (w >> 1) * 64, wc = (w & 1) * 64;
    const int lrow = l & 15;
    const int hi = l >> 4;
    const int lk = hi * 8;
    const int sr = l >> 3;
    const int sc = (l & 7) * 8;
    f32x4 acc[4][4] = {};

    for (int k0 = 0; k0 < 1024; k0 += 64) {
#pragma unroll
        for (int i = 0; i < 4; ++i) {
            const int chunk = w * 4 + i;
            const int r = chunk * 8 + sr;
            GLL(A  + (size_t)(brow + r) * 1024 + k0 + sc, lA + chunk * 512);
            GLL(Bw + (size_t)(bcol + r) * 1024 + k0 + sc, lB + chunk * 512);
        }
        asm volatile("s_waitcnt vmcnt(0)" ::: "memory");
        __syncthreads();
#pragma unroll
        for (int kk = 0; kk < 2; ++kk) {
            short8 af[4], bfr[4];
#pragma unroll
            for (int m = 0; m < 4; ++m)
                af[m] = *(const short8*)(lA + (wr + m * 16 + lrow) * 64 + kk * 32 + lk);
#pragma unroll
            for (int n = 0; n < 4; ++n) {
                const int row = wc + n * 16 + lrow;
                const int pb = (kk * 4 + hi) ^ (row & 7);     // W is pre-swizzled
                bfr[n] = *(const short8*)((const char*)lB + row * 128 + (pb << 4));
            }
#pragma unroll
            for (int m = 0; m < 4; ++m)
#pragma unroll
                for (int n = 0; n < 4; ++n)
                    acc[m][n] = __builtin_amdgcn_mfma_f32_16x16x32_bf16(af[m], bfr[n], acc[m][n], 0, 0, 0);
        }
        __syncthreads();
    }

#pragma unroll
    for (int m = 0; m < 4; ++m) {
#pragma unroll
        for (int n = 0; n < 4; ++n) {
            const int i0 = brow + wr + m * 16 + (l >> 4) * 4;
            const int j  = bcol + wc + n * 16 + lrow;
            const float bj = bias[j];
#pragma unroll
            for (int t = 0; t < 4; ++t)
                Cout[(size_t)(i0 + t) * DM + j] = acc[m][n][t] + bj;
        }
    }
}

// ---------------- causal flash attention (round-7, unchanged) ----------------
__global__ __launch_bounds__(256) void attn_kernel(
        const unsigned short* __restrict__ Q,
        const unsigned short* __restrict__ K,
        const unsigned short* __restrict__ Vt,
        unsigned short* __restrict__ AO)
{
    const int flat = blockIdx.y * 16 + blockIdx.x;      // grid (16, 64)
    const int r8 = flat & 7, k8 = flat >> 3;
    const int bh = r8 * 8 + (k8 & 7);                   // 8 heads per XCD-residue (L2 share)
    const int qchunk = 15 - (k8 >> 3);                  // LPT: long blocks first
    const int tid = threadIdx.x;
    const int w = tid >> 6, l = tid & 63;
    const int ln = l & 31, h = l >> 5;
    const int qb = qchunk * 128;
    const int q0w = qb + w * 32;

    __shared__ __align__(16) char lK[2][4096];
    __shared__ __align__(16) char lV[2][4096];

    const unsigned short* Qp = Q  + ((size_t)bh * SS + q0w) * DKK;
    const unsigned short* Kp = K  + (size_t)bh * SS * DKK;
    const unsigned short* Vp = Vt + (size_t)bh * DKK * SS;

    const int srow = tid >> 3, scb = tid & 7;
    const int swb = srow * 128 + ((scb * 16) ^ ((srow & 7) << 4));
    const unsigned short* ksrc = Kp + srow * DKK + scb * 8;            // + t*2048
    const int vd = (scb < 4) ? srow : (srow + 32);
    const unsigned short* vsrc = Vp + (size_t)vd * SS + (scb & 3) * 8; // + t*32

    int ka[4], va[4];
#pragma unroll
    for (int ks = 0; ks < 4; ++ks)
        ka[ks] = ln * 128 + ((ks * 32 + h * 16) ^ ((ln & 7) << 4));
#pragma unroll
    for (int c = 0; c < 4; ++c)
        va[c] = ln * 128 + ((c * 32 + h * 16) ^ ((ln & 7) << 4));

    short8 qf[4];
#pragma unroll
    for (int ks = 0; ks < 4; ++ks)
        qf[ks] = *(const short8*)(Qp + (size_t)ln * DKK + ks * 16 + h * 8);

    f32x16 o0 = {}, o1 = {};
    float lsum = 0.f;

    const int Tc = qb / 32;
    const int NT = Tc + 4;

    auto compute = [&](int t, int buf) {
        const char* kb = lK[buf];
        const char* vb = lV[buf];
        short8 kf[4];
#pragma unroll
        for (int ks = 0; ks < 4; ++ks) kf[ks] = *(const short8*)(kb + ka[ks]);

        f32x16 s = {};
        __builtin_amdgcn_s_setprio(1);
#pragma unroll
        for (int ks = 0; ks < 4; ++ks)
            s = __builtin_amdgcn_mfma_f32_32x32x16_bf16(kf[ks], qf[ks], s, 0, 0, 0);
        __builtin_amdgcn_s_setprio(0);

        const bool diag = (t == Tc + w);
#pragma unroll
        for (int r = 0; r < 16; ++r) {
            float e;
            asm("v_exp_f32 %0, %1" : "=v"(e) : "v"(s[r]));   // 2^s (Q pre-scaled)
            if (diag) {
                const int crow = (r & 3) + 8 * (r >> 2) + 4 * h;
                e = (crow > ln) ? 0.f : e;
            }
            s[r] = e;
            lsum += e;
        }

        uint32_t pk[8];
#pragma unroll
        for (int i = 0; i < 8; ++i) {
            uint32_t d;
            asm("v_cvt_pk_bf16_f32 %0, %1, %2" : "=v"(d) : "v"(s[2 * i]), "v"(s[2 * i + 1]));
            pk[i] = d;
        }
        asm("v_permlane32_swap_b32 %0, %1" : "+v"(pk[0]), "+v"(pk[2]));
        asm("v_permlane32_swap_b32 %0, %1" : "+v"(pk[1]), "+v"(pk[3]));
        asm("v_permlane32_swap_b32 %0, %1" : "+v"(pk[4]), "+v"(pk[6]));
        asm("v_permlane32_swap_b32 %0, %1" : "+v"(pk[5]), "+v"(pk[7]));

        union Ux { uint32_t u[4]; short8 s8; } pa0, pa1;
        pa0.u[0] = pk[0]; pa0.u[1] = pk[1]; pa0.u[2] = pk[2]; pa0.u[3] = pk[3];
        pa1.u[0] = pk[4]; pa1.u[1] = pk[5]; pa1.u[2] = pk[6]; pa1.u[3] = pk[7];

        short8 vf00 = *(const short8*)(vb + va[0]);
        short8 vf10 = *(const short8*)(vb + va[1]);
        short8 vf01 = *(const short8*)(vb + va[2]);
        short8 vf11 = *(const short8*)(vb + va[3]);

        __builtin_amdgcn_s_setprio(1);
        o0 = __builtin_amdgcn_mfma_f32_32x32x16_bf16(pa0.s8, vf00, o0, 0, 0, 0);
        o0 = __builtin_amdgcn_mfma_f32_32x32x16_bf16(pa1.s8, vf10, o0, 0, 0, 0);
        o1 = __builtin_amdgcn_mfma_f32_32x32x16_bf16(pa0.s8, vf01, o1, 0, 0, 0);
        o1 = __builtin_amdgcn_mfma_f32_32x32x16_bf16(pa1.s8, vf11, o1, 0, 0, 0);
        __builtin_amdgcn_s_setprio(0);
    };

    short8 kA = *(const short8*)(ksrc);
    short8 vA = *(const short8*)(vsrc);
    *(short8*)(&lK[0][swb]) = kA;
    *(short8*)(&lV[0][swb]) = vA;
    kA = *(const short8*)(ksrc + 2048);
    vA = *(const short8*)(vsrc + 32);
    short8 kB = {}, vB = {};
    __syncthreads();

    int t = 0, buf = 0;
    for (;;) {
        if (t + 2 < NT) {
            kB = *(const short8*)(ksrc + (size_t)(t + 2) * 2048);
            vB = *(const short8*)(vsrc + (size_t)(t + 2) * 32);
        }
        if (t <= Tc + w) compute(t, buf);
        if (t + 1 < NT) {
            *(short8*)(&lK[buf ^ 1][swb]) = kA;
            *(short8*)(&lV[buf ^ 1][swb]) = vA;
        }
        __syncthreads();
        buf ^= 1;
        if (++t == NT) break;

        if (t + 2 < NT) {
            kA = *(const short8*)(ksrc + (size_t)(t + 2) * 2048);
            vA = *(const short8*)(vsrc + (size_t)(t + 2) * 32);
        }
        if (t <= Tc + w) compute(t, buf);
        if (t + 1 < NT) {
            *(short8*)(&lK[buf ^ 1][swb]) = kB;
            *(short8*)(&lV[buf ^ 1][swb]) = vB;
        }
        __syncthreads();
        buf ^= 1;
        if (++t == NT) break;
    }

    lsum += __shfl_xor(lsum, 32, 64);
    const float rcp = 1.0f / lsum;

    const int bb = bh >> 4, hh = bh & 15;
#pragma unroll
    for (int r = 0; r < 16; ++r) {
        const int crow = (r & 3) + 8 * (r >> 2) + 4 * h;
        const float rl = __shfl(rcp, crow, 64);
        const size_t row = (size_t)(bb * SS + q0w + crow) * DM + hh * DKK;
        AO[row + ln]      = f2bf(o0[r] * rl);
        AO[row + 32 + ln] = f2bf(o1[r] * rl);
    }
}

extern "C" void kernel_launch(void* const* d_in, const int* in_sizes, int n_in,
                              void* d_out, int out_size, void* d_ws, size_t ws_size,
                              hipStream_t stream)
{
    const float* query  = (const float*)d_in[0];
    const float* key_in = (const float*)d_in[1];
    const float* value  = (const float*)d_in[2];
    const float* Wq = (const float*)d_in[3];
    const float* bq = (const float*)d_in[4];
    const float* Wk = (const float*)d_in[5];
    const float* bk = (const float*)d_in[6];
    const float* Wv = (const float*)d_in[7];
    const float* bv = (const float*)d_in[8];
    const float* Wo = (const float*)d_in[9];
    const float* bo = (const float*)d_in[10];

    const size_t NACT = (size_t)BB * SS * DM;   // 8388608
    const size_t NWT  = (size_t)DM * DM;        // 1048576

    unsigned short* ws  = (unsigned short*)d_ws;
    unsigned short* wqb = ws;
    unsigned short* wkb = wqb + NWT;
    unsigned short* wvb = wkb + NWT;
    unsigned short* wob = wvb + NWT;
    unsigned short* Qb  = wob + NWT;
    unsigned short* Kb  = Qb + NACT;
    unsigned short* Vtb = Kb + NACT;
    unsigned short* AOb = Vtb + NACT;

    cvt_w<<<2048, 256, 0, stream>>>(Wq, Wk, Wv, Wo, ws);

    const float QSCALE = 0.125f * 1.44269504088896f;   // 1/sqrt(64) * log2(e)
    dim3 gq(DM / 128, (BB * SS) / 128, 3);   // (8, 64, 3)
    gemm_qkv<<<gq, 256, 0, stream>>>(query, key_in, value, wqb, wkb, wvb,
                                     bq, bk, bv, Qb, Kb, Vtb, QSCALE);

    attn_kernel<<<dim3(16, 64), 256, 0, stream>>>(Qb, Kb, Vtb, AOb);

    dim3 gg(DM / 128, (BB * SS) / 128);   // (8, 64)
    gemm_out<<<gg, 256, 0, stream>>>(AOb, wob, bo, (float*)d_out);
}

// Round 10
// 162.458 us; speedup vs baseline: 1.3080x; 1.0257x over previous
//
#include <hip/hip_runtime.h>
#include <hip/hip_bf16.h>
#include <cstdint>

#define DM   1024
#define NH   16
#define DKK  64
#define BB   4
#define SS   2048

typedef __attribute__((ext_vector_type(8)))  short short8;
typedef __attribute__((ext_vector_type(4)))  float f32x4;
typedef __attribute__((ext_vector_type(16))) float f32x16;

__device__ __forceinline__ unsigned short f2bf(float f) {
    union { float f; uint32_t u; } v; v.f = f;
    uint32_t u = v.u;
    uint32_t r = (u + 0x7FFFu + ((u >> 16) & 1u)) >> 16;   // RNE
    return (unsigned short)r;
}

#define GLL(src, dst) __builtin_amdgcn_global_load_lds(                      \
        (__attribute__((address_space(1))) void*)(src),                      \
        (__attribute__((address_space(3))) void*)(dst), 16, 0, 0)

// ---------------- fp32 -> bf16 convert + PRE-SWIZZLE (4 weight matrices) ----------------
// W_sw[j][kb*8..] = W[j][kbs*8..], kbs = (kb&~7)|((kb^j)&7): linear global_load_lds then
// yields the T2-swizzled LDS tile.
__global__ void cvt_w(const float* __restrict__ wq, const float* __restrict__ wk,
                      const float* __restrict__ wv, const float* __restrict__ wo,
                      unsigned short* __restrict__ dst)
{
    int i = blockIdx.x * 256 + threadIdx.x;      // 16B-block id: 4 * 1024 * 128
    int a = i >> 17;
    int r = i & 131071;
    int j = r >> 7, kb = r & 127;
    int kbs = (kb & ~7) | ((kb ^ j) & 7);
    const float* s = (a == 0 ? wq : a == 1 ? wk : a == 2 ? wv : wo) + (size_t)j * 1024 + kbs * 8;
    float4 f0 = *(const float4*)(s);
    float4 f1 = *(const float4*)(s + 4);
    union { uint32_t u[4]; short8 s8; } c;
    asm("v_cvt_pk_bf16_f32 %0, %1, %2" : "=v"(c.u[0]) : "v"(f0.x), "v"(f0.y));
    asm("v_cvt_pk_bf16_f32 %0, %1, %2" : "=v"(c.u[1]) : "v"(f0.z), "v"(f0.w));
    asm("v_cvt_pk_bf16_f32 %0, %1, %2" : "=v"(c.u[2]) : "v"(f1.x), "v"(f1.y));
    asm("v_cvt_pk_bf16_f32 %0, %1, %2" : "=v"(c.u[3]) : "v"(f1.z), "v"(f1.w));
    *(short8*)(dst + ((size_t)a << 20) + (size_t)j * 1024 + kb * 8) = c.s8;
}

// ---------------- merged QKV GEMM: fused A cvt, T2 swizzle, depth-2 A prefetch ----------------
__global__ __launch_bounds__(256) void gemm_qkv(
        const float* __restrict__ Aq, const float* __restrict__ Ak, const float* __restrict__ Av,
        const unsigned short* __restrict__ Wq, const unsigned short* __restrict__ Wk,
        const unsigned short* __restrict__ Wv,
        const float* __restrict__ bq, const float* __restrict__ bk, const float* __restrict__ bv,
        unsigned short* __restrict__ Qo, unsigned short* __restrict__ Ko,
        unsigned short* __restrict__ Vo, const float qscale)
{
    const int orig = blockIdx.z * 512 + blockIdx.y * 8 + blockIdx.x;
    const int wid  = (orig & 7) * 192 + (orig >> 3);     // bijective XCD swizzle
    const int z    = wid >> 9;
    const int rem  = wid & 511;
    const int brow = (rem >> 3) * 128;
    const int bcol = (rem & 7) * 128;

    const float* A           = (z == 0) ? Aq : (z == 1) ? Ak : Av;
    const unsigned short* Bw = (z == 0) ? Wq : (z == 1) ? Wk : Wv;
    const float* bias        = (z == 0) ? bq : (z == 1) ? bk : bv;

    __shared__ __align__(16) unsigned short lA[128 * 64];
    __shared__ __align__(16) unsigned short lB[2][128 * 64];

    const int tid = threadIdx.x;
    const int w = tid >> 6, l = tid & 63;
    const int wr = (w >> 1) * 64, wc = (w & 1) * 64;
    const int lrow = l & 15;
    const int hi = l >> 4;
    const int sr = l >> 3, scb = l & 7;

    const float* aga[4];
    const unsigned short* bga[4];
    int awb[4], lbo[4];
#pragma unroll
    for (int i = 0; i < 4; ++i) {
        const int chunk = w * 4 + i;
        const int r = chunk * 8 + sr;
        aga[i] = A + (size_t)(brow + r) * 1024 + scb * 8;
        bga[i] = Bw + (size_t)(bcol + r) * 1024 + scb * 8;
        awb[i] = chunk * 1024 + sr * 128 + ((scb ^ sr) << 4);
        lbo[i] = chunk * 512;
    }

    f32x4 aX[4][2], aY[4][2];
    f32x4 acc[4][4] = {};

    // prologue: B(0) -> lB[0]; X <- A(0); Y <- A(1)
#pragma unroll
    for (int i = 0; i < 4; ++i) GLL(bga[i], lB[0] + lbo[i]);
#pragma unroll
    for (int i = 0; i < 4; ++i) { aX[i][0] = *(const f32x4*)(aga[i]); aX[i][1] = *(const f32x4*)(aga[i] + 4); }
#pragma unroll
    for (int i = 0; i < 4; ++i) { aY[i][0] = *(const f32x4*)(aga[i] + 64); aY[i][1] = *(const f32x4*)(aga[i] + 64 + 4); }

#define QKV_CVT(CUR)                                                                              \
    _Pragma("unroll")                                                                             \
    for (int i = 0; i < 4; ++i) {                                                                 \
        union { uint32_t u[4]; short8 s8; } c;                                                    \
        asm("v_cvt_pk_bf16_f32 %0, %1, %2" : "=v"(c.u[0]) : "v"(CUR[i][0][0]), "v"(CUR[i][0][1]));\
        asm("v_cvt_pk_bf16_f32 %0, %1, %2" : "=v"(c.u[1]) : "v"(CUR[i][0][2]), "v"(CUR[i][0][3]));\
        asm("v_cvt_pk_bf16_f32 %0, %1, %2" : "=v"(c.u[2]) : "v"(CUR[i][1][0]), "v"(CUR[i][1][1]));\
        asm("v_cvt_pk_bf16_f32 %0, %1, %2" : "=v"(c.u[3]) : "v"(CUR[i][1][2]), "v"(CUR[i][1][3]));\
        *(short8*)((char*)lA + awb[i]) = c.s8;                                                    \
    }

#define QKV_MFMA(LB)                                                                              \
    {                                                                                             \
        const unsigned short* lb = (LB);                                                          \
        __builtin_amdgcn_s_setprio(1);                                                            \
        _Pragma("unroll")                                                                         \
        for (int kk = 0; kk < 2; ++kk) {                                                          \
            short8 af[4], bf[4];                                                                  \
            _Pragma("unroll")                                                                     \
            for (int m = 0; m < 4; ++m) {                                                         \
                const int row = wr + m * 16 + lrow;                                               \
                const int pb = (kk * 4 + hi) ^ (row & 7);                                         \
                af[m] = *(const short8*)((const char*)lA + row * 128 + (pb << 4));                \
            }                                                                                     \
            _Pragma("unroll")                                                                     \
            for (int n = 0; n < 4; ++n) {                                                         \
                const int row = wc + n * 16 + lrow;                                               \
                const int pb = (kk * 4 + hi) ^ (row & 7);                                         \
                bf[n] = *(const short8*)((const char*)lb + row * 128 + (pb << 4));                \
            }                                                                                     \
            _Pragma("unroll")                                                                     \
            for (int m = 0; m < 4; ++m)                                                           \
                _Pragma("unroll")                                                                 \
                for (int n = 0; n < 4; ++n)                                                       \
                    acc[m][n] = __builtin_amdgcn_mfma_f32_16x16x32_bf16(af[m], bf[n], acc[m][n], 0, 0, 0); \
        }                                                                                         \
        __builtin_amdgcn_s_setprio(0);                                                            \
    }

    // main loop: t = 0..13, X/Y alternate; A depth-2, B depth-1
    for (int t = 0; t < 14; t += 2) {
        // --- even t: consume X, reload X <- A(t+2), B(t+1)->lB[1], MFMA lB[0]
        QKV_CVT(aX);
        {
            const int ko = (t + 2) * 64;
#pragma unroll
            for (int i = 0; i < 4; ++i) { aX[i][0] = *(const f32x4*)(aga[i] + ko); aX[i][1] = *(const f32x4*)(aga[i] + ko + 4); }
            const int kb = (t + 1) * 64;
#pragma unroll
            for (int i = 0; i < 4; ++i) GLL(bga[i] + kb, lB[1] + lbo[i]);
        }
        asm volatile("s_waitcnt vmcnt(12) lgkmcnt(0)" ::: "memory");
        __builtin_amdgcn_s_barrier();
        QKV_MFMA(lB[0]);
        asm volatile("" ::: "memory");
        __builtin_amdgcn_s_barrier();
        // --- odd t+1: consume Y, reload Y <- A(t+3), B(t+2)->lB[0], MFMA lB[1]
        QKV_CVT(aY);
        {
            const int ko = (t + 3) * 64;
#pragma unroll
            for (int i = 0; i < 4; ++i) { aY[i][0] = *(const f32x4*)(aga[i] + ko); aY[i][1] = *(const f32x4*)(aga[i] + ko + 4); }
            const int kb = (t + 2) * 64;
#pragma unroll
            for (int i = 0; i < 4; ++i) GLL(bga[i] + kb, lB[0] + lbo[i]);
        }
        asm volatile("s_waitcnt vmcnt(12) lgkmcnt(0)" ::: "memory");
        __builtin_amdgcn_s_barrier();
        QKV_MFMA(lB[1]);
        asm volatile("" ::: "memory");
        __builtin_amdgcn_s_barrier();
    }
    // t = 14: consume X(14); B(15)->lB[1]; MFMA lB[0]
    QKV_CVT(aX);
#pragma unroll
    for (int i = 0; i < 4; ++i) GLL(bga[i] + 15 * 64, lB[1] + lbo[i]);
    asm volatile("s_waitcnt vmcnt(4) lgkmcnt(0)" ::: "memory");
    __builtin_amdgcn_s_barrier();
    QKV_MFMA(lB[0]);
    asm volatile("" ::: "memory");
    __builtin_amdgcn_s_barrier();
    // t = 15: consume Y(15); MFMA lB[1]
    QKV_CVT(aY);
    asm volatile("s_waitcnt vmcnt(0) lgkmcnt(0)" ::: "memory");
    __builtin_amdgcn_s_barrier();
    QKV_MFMA(lB[1]);

    const float ascale = (z == 0) ? qscale : 1.0f;
#pragma unroll
    for (int m = 0; m < 4; ++m) {
#pragma unroll
        for (int n = 0; n < 4; ++n) {
            const int i0 = brow + wr + m * 16 + (l >> 4) * 4;
            const int j  = bcol + wc + n * 16 + lrow;
            const float bj = bias[j];
            const int hh = j >> 6, d = j & 63;
            if (z < 2) {
                unsigned short* Cb = (z == 0) ? Qo : Ko;
#pragma unroll
                for (int t = 0; t < 4; ++t) {
                    const int i = i0 + t;
                    const int b = i >> 11, s = i & 2047;
                    Cb[(((size_t)(b * NH + hh) * SS) + s) * DKK + d] = f2bf((acc[m][n][t] + bj) * ascale);
                }
            } else {   // V^T
                const int b = i0 >> 11, s0 = i0 & 2047;
                ushort4 pk;
                pk.x = f2bf(acc[m][n][0] + bj);
                pk.y = f2bf(acc[m][n][1] + bj);
                pk.z = f2bf(acc[m][n][2] + bj);
                pk.w = f2bf(acc[m][n][3] + bj);
                *(ushort4*)(Vo + (((size_t)(b * NH + hh) * DKK) + d) * SS + s0) = pk;
            }
        }
    }
#undef QKV_CVT
#undef QKV_MFMA
}

// ---------------- final projection GEMM: bf16 A reg-staged swizzled, depth-2, fp32 out ------
__global__ __launch_bounds__(256) void gemm_out(
        const unsigned short* __restrict__ A,
        const unsigned short* __restrict__ Bw,
        const float* __restrict__ bias,
        float* __restrict__ Cout)
{
    const int orig = blockIdx.y * 8 + blockIdx.x;
    const int wid  = (orig & 7) * 64 + (orig >> 3);
    const int brow = (wid >> 3) * 128;
    const int bcol = (wid & 7) * 128;

    __shared__ __align__(16) unsigned short lA[128 * 64];
    __shared__ __align__(16) unsigned short lB[2][128 * 64];

    const int tid = threadIdx.x;
    const int w = tid >> 6, l = tid & 63;
    const int wr = (w >> 1) * 64, wc = (w & 1) * 64;
    const int lrow = l & 15;
    const int hi = l >> 4;
    const int sr = l >> 3, scb = l & 7;

    const unsigned short* aga[4];
    const unsigned short* bga[4];
    int awb[4], lbo[4];
#pragma unroll
    for (int i = 0; i < 4; ++i) {
        const int chunk = w * 4 + i;
        const int r = chunk * 8 + sr;
        aga[i] = A  + (size_t)(brow + r) * 1024 + scb * 8;
        bga[i] = Bw + (size_t)(bcol + r) * 1024 + scb * 8;
        awb[i] = chunk * 1024 + sr * 128 + ((scb ^ sr) << 4);
        lbo[i] = chunk * 512;
    }

    short8 aX[4], aY[4];
    f32x4 acc[4][4] = {};

#pragma unroll
    for (int i = 0; i < 4; ++i) GLL(bga[i], lB[0] + lbo[i]);
#pragma unroll
    for (int i = 0; i < 4; ++i) aX[i] = *(const short8*)(aga[i]);
#pragma unroll
    for (int i = 0; i < 4; ++i) aY[i] = *(const short8*)(aga[i] + 64);

#define OUT_WR(CUR)                                                     \
    _Pragma("unroll")                                                   \
    for (int i = 0; i < 4; ++i)                                         \
        *(short8*)((char*)lA + awb[i]) = CUR[i];

#define OUT_MFMA(LB)                                                                              \
    {                                                                                             \
        const unsigned short* lb = (LB);                                                          \
        __builtin_amdgcn_s_setprio(1);                                                            \
        _Pragma("unroll")                                                                         \
        for (int kk = 0; kk < 2; ++kk) {                                                          \
            short8 af[4], bf[4];                                                                  \
            _Pragma("unroll")                                                                     \
            for (int m = 0; m < 4; ++m) {                                                         \
                const int row = wr + m * 16 + lrow;                                               \
                const int pb = (kk * 4 + hi) ^ (row & 7);                                         \
                af[m] = *(const short8*)((const char*)lA + row * 128 + (pb << 4));                \
            }                                                                                     \
            _Pragma("unroll")                                                                     \
            for (int n = 0; n < 4; ++n) {                                                         \
                const int row = wc + n * 16 + lrow;                                               \
                const int pb = (kk * 4 + hi) ^ (row & 7);                                         \
                bf[n] = *(const short8*)((const char*)lb + row * 128 + (pb << 4));                \
            }                                                                                     \
            _Pragma("unroll")                                                                     \
            for (int m = 0; m < 4; ++m)                                                           \
                _Pragma("unroll")                                                                 \
                for (int n = 0; n < 4; ++n)                                                       \
                    acc[m][n] = __builtin_amdgcn_mfma_f32_16x16x32_bf16(af[m], bf[n], acc[m][n], 0, 0, 0); \
        }                                                                                         \
        __builtin_amdgcn_s_setprio(0);                                                            \
    }

    for (int t = 0; t < 14; t += 2) {
        OUT_WR(aX);
        {
            const int ko = (t + 2) * 64;
#pragma unroll
            for (int i = 0; i < 4; ++i) aX[i] = *(const short8*)(aga[i] + ko);
            const int kb = (t + 1) * 64;
#pragma unroll
            for (int i = 0; i < 4; ++i) GLL(bga[i] + kb, lB[1] + lbo[i]);
        }
        asm volatile("s_waitcnt vmcnt(8) lgkmcnt(0)" ::: "memory");
        __builtin_amdgcn_s_barrier();
        OUT_MFMA(lB[0]);
        asm volatile("" ::: "memory");
        __builtin_amdgcn_s_barrier();

        OUT_WR(aY);
        {
            const int ko = (t + 3) * 64;
#pragma unroll
            for (int i = 0; i < 4; ++i) aY[i] = *(const short8*)(aga[i] + ko);
            const int kb = (t + 2) * 64;
#pragma unroll
            for (int i = 0; i < 4; ++i) GLL(bga[i] + kb, lB[0] + lbo[i]);
        }
        asm volatile("s_waitcnt vmcnt(8) lgkmcnt(0)" ::: "memory");
        __builtin_amdgcn_s_barrier();
        OUT_MFMA(lB[1]);
        asm volatile("" ::: "memory");
        __builtin_amdgcn_s_barrier();
    }
    OUT_WR(aX);
#pragma unroll
    for (int i = 0; i < 4; ++i) GLL(bga[i] + 15 * 64, lB[1] + lbo[i]);
    asm volatile("s_waitcnt vmcnt(4) lgkmcnt(0)" ::: "memory");
    __builtin_amdgcn_s_barrier();
    OUT_MFMA(lB[0]);
    asm volatile("" ::: "memory");
    __builtin_amdgcn_s_barrier();
    OUT_WR(aY);
    asm volatile("s_waitcnt vmcnt(0) lgkmcnt(0)" ::: "memory");
    __builtin_amdgcn_s_barrier();
    OUT_MFMA(lB[1]);

#pragma unroll
    for (int m = 0; m < 4; ++m) {
#pragma unroll
        for (int n = 0; n < 4; ++n) {
            const int i0 = brow + wr + m * 16 + (l >> 4) * 4;
            const int j  = bcol + wc + n * 16 + lrow;
            const float bj = bias[j];
#pragma unroll
            for (int t = 0; t < 4; ++t)
                Cout[(size_t)(i0 + t) * DM + j] = acc[m][n][t] + bj;
        }
    }
#undef OUT_WR
#undef OUT_MFMA
}

// ---------------- causal flash attention (round-7, unchanged) ----------------
__global__ __launch_bounds__(256) void attn_kernel(
        const unsigned short* __restrict__ Q,
        const unsigned short* __restrict__ K,
        const unsigned short* __restrict__ Vt,
        unsigned short* __restrict__ AO)
{
    const int flat = blockIdx.y * 16 + blockIdx.x;      // grid (16, 64)
    const int r8 = flat & 7, k8 = flat >> 3;
    const int bh = r8 * 8 + (k8 & 7);                   // 8 heads per XCD-residue (L2 share)
    const int qchunk = 15 - (k8 >> 3);                  // LPT: long blocks first
    const int tid = threadIdx.x;
    const int w = tid >> 6, l = tid & 63;
    const int ln = l & 31, h = l >> 5;
    const int qb = qchunk * 128;
    const int q0w = qb + w * 32;

    __shared__ __align__(16) char lK[2][4096];
    __shared__ __align__(16) char lV[2][4096];

    const unsigned short* Qp = Q  + ((size_t)bh * SS + q0w) * DKK;
    const unsigned short* Kp = K  + (size_t)bh * SS * DKK;
    const unsigned short* Vp = Vt + (size_t)bh * DKK * SS;

    const int srow = tid >> 3, scb = tid & 7;
    const int swb = srow * 128 + ((scb * 16) ^ ((srow & 7) << 4));
    const unsigned short* ksrc = Kp + srow * DKK + scb * 8;            // + t*2048
    const int vd = (scb < 4) ? srow : (srow + 32);
    const unsigned short* vsrc = Vp + (size_t)vd * SS + (scb & 3) * 8; // + t*32

    int ka[4], va[4];
#pragma unroll
    for (int ks = 0; ks < 4; ++ks)
        ka[ks] = ln * 128 + ((ks * 32 + h * 16) ^ ((ln & 7) << 4));
#pragma unroll
    for (int c = 0; c < 4; ++c)
        va[c] = ln * 128 + ((c * 32 + h * 16) ^ ((ln & 7) << 4));

    short8 qf[4];
#pragma unroll
    for (int ks = 0; ks < 4; ++ks)
        qf[ks] = *(const short8*)(Qp + (size_t)ln * DKK + ks * 16 + h * 8);

    f32x16 o0 = {}, o1 = {};
    float lsum = 0.f;

    const int Tc = qb / 32;
    const int NT = Tc + 4;

    auto compute = [&](int t, int buf) {
        const char* kb = lK[buf];
        const char* vb = lV[buf];
        short8 kf[4];
#pragma unroll
        for (int ks = 0; ks < 4; ++ks) kf[ks] = *(const short8*)(kb + ka[ks]);

        f32x16 s = {};
        __builtin_amdgcn_s_setprio(1);
#pragma unroll
        for (int ks = 0; ks < 4; ++ks)
            s = __builtin_amdgcn_mfma_f32_32x32x16_bf16(kf[ks], qf[ks], s, 0, 0, 0);
        __builtin_amdgcn_s_setprio(0);

        const bool diag = (t == Tc + w);
#pragma unroll
        for (int r = 0; r < 16; ++r) {
            float e;
            asm("v_exp_f32 %0, %1" : "=v"(e) : "v"(s[r]));   // 2^s (Q pre-scaled)
            if (diag) {
                const int crow = (r & 3) + 8 * (r >> 2) + 4 * h;
                e = (crow > ln) ? 0.f : e;
            }
            s[r] = e;
            lsum += e;
        }

        uint32_t pk[8];
#pragma unroll
        for (int i = 0; i < 8; ++i) {
            uint32_t d;
            asm("v_cvt_pk_bf16_f32 %0, %1, %2" : "=v"(d) : "v"(s[2 * i]), "v"(s[2 * i + 1]));
            pk[i] = d;
        }
        asm("v_permlane32_swap_b32 %0, %1" : "+v"(pk[0]), "+v"(pk[2]));
        asm("v_permlane32_swap_b32 %0, %1" : "+v"(pk[1]), "+v"(pk[3]));
        asm("v_permlane32_swap_b32 %0, %1" : "+v"(pk[4]), "+v"(pk[6]));
        asm("v_permlane32_swap_b32 %0, %1" : "+v"(pk[5]), "+v"(pk[7]));

        union Ux { uint32_t u[4]; short8 s8; } pa0, pa1;
        pa0.u[0] = pk[0]; pa0.u[1] = pk[1]; pa0.u[2] = pk[2]; pa0.u[3] = pk[3];
        pa1.u[0] = pk[4]; pa1.u[1] = pk[5]; pa1.u[2] = pk[6]; pa1.u[3] = pk[7];

        short8 vf00 = *(const short8*)(vb + va[0]);
        short8 vf10 = *(const short8*)(vb + va[1]);
        short8 vf01 = *(const short8*)(vb + va[2]);
        short8 vf11 = *(const short8*)(vb + va[3]);

        __builtin_amdgcn_s_setprio(1);
        o0 = __builtin_amdgcn_mfma_f32_32x32x16_bf16(pa0.s8, vf00, o0, 0, 0, 0);
        o0 = __builtin_amdgcn_mfma_f32_32x32x16_bf16(pa1.s8, vf10, o0, 0, 0, 0);
        o1 = __builtin_amdgcn_mfma_f32_32x32x16_bf16(pa0.s8, vf01, o1, 0, 0, 0);
        o1 = __builtin_amdgcn_mfma_f32_32x32x16_bf16(pa1.s8, vf11, o1, 0, 0, 0);
        __builtin_amdgcn_s_setprio(0);
    };

    short8 kA = *(const short8*)(ksrc);
    short8 vA = *(const short8*)(vsrc);
    *(short8*)(&lK[0][swb]) = kA;
    *(short8*)(&lV[0][swb]) = vA;
    kA = *(const short8*)(ksrc + 2048);
    vA = *(const short8*)(vsrc + 32);
    short8 kB = {}, vB = {};
    __syncthreads();

    int t = 0, buf = 0;
    for (;;) {
        if (t + 2 < NT) {
            kB = *(const short8*)(ksrc + (size_t)(t + 2) * 2048);
            vB = *(const short8*)(vsrc + (size_t)(t + 2) * 32);
        }
        if (t <= Tc + w) compute(t, buf);
        if (t + 1 < NT) {
            *(short8*)(&lK[buf ^ 1][swb]) = kA;
            *(short8*)(&lV[buf ^ 1][swb]) = vA;
        }
        __syncthreads();
        buf ^= 1;
        if (++t == NT) break;

        if (t + 2 < NT) {
            kA = *(const short8*)(ksrc + (size_t)(t + 2) * 2048);
            vA = *(const short8*)(vsrc + (size_t)(t + 2) * 32);
        }
        if (t <= Tc + w) compute(t, buf);
        if (t + 1 < NT) {
            *(short8*)(&lK[buf ^ 1][swb]) = kB;
            *(short8*)(&lV[buf ^ 1][swb]) = vB;
        }
        __syncthreads();
        buf ^= 1;
        if (++t == NT) break;
    }

    lsum += __shfl_xor(lsum, 32, 64);
    const float rcp = 1.0f / lsum;

    const int bb = bh >> 4, hh = bh & 15;
#pragma unroll
    for (int r = 0; r < 16; ++r) {
        const int crow = (r & 3) + 8 * (r >> 2) + 4 * h;
        const float rl = __shfl(rcp, crow, 64);
        const size_t row = (size_t)(bb * SS + q0w + crow) * DM + hh * DKK;
        AO[row + ln]      = f2bf(o0[r] * rl);
        AO[row + 32 + ln] = f2bf(o1[r] * rl);
    }
}

extern "C" void kernel_launch(void* const* d_in, const int* in_sizes, int n_in,
                              void* d_out, int out_size, void* d_ws, size_t ws_size,
                              hipStream_t stream)
{
    const float* query  = (const float*)d_in[0];
    const float* key_in = (const float*)d_in[1];
    const float* value  = (const float*)d_in[2];
    const float* Wq = (const float*)d_in[3];
    const float* bq = (const float*)d_in[4];
    const float* Wk = (const float*)d_in[5];
    const float* bk = (const float*)d_in[6];
    const float* Wv = (const float*)d_in[7];
    const float* bv = (const float*)d_in[8];
    const float* Wo = (const float*)d_in[9];
    const float* bo = (const float*)d_in[10];

    const size_t NACT = (size_t)BB * SS * DM;   // 8388608
    const size_t NWT  = (size_t)DM * DM;        // 1048576

    unsigned short* ws  = (unsigned short*)d_ws;
    unsigned short* wqb = ws;
    unsigned short* wkb = wqb + NWT;
    unsigned short* wvb = wkb + NWT;
    unsigned short* wob = wvb + NWT;
    unsigned short* Qb  = wob + NWT;
    unsigned short* Kb  = Qb + NACT;
    unsigned short* Vtb = Kb + NACT;
    unsigned short* AOb = Vtb + NACT;

    cvt_w<<<2048, 256, 0, stream>>>(Wq, Wk, Wv, Wo, ws);

    const float QSCALE = 0.125f * 1.44269504088896f;   // 1/sqrt(64) * log2(e)
    dim3 gq(DM / 128, (BB * SS) / 128, 3);   // (8, 64, 3)
    gemm_qkv<<<gq, 256, 0, stream>>>(query, key_in, value, wqb, wkb, wvb,
                                     bq, bk, bv, Qb, Kb, Vtb, QSCALE);

    attn_kernel<<<dim3(16, 64), 256, 0, stream>>>(Qb, Kb, Vtb, AOb);

    dim3 gg(DM / 128, (BB * SS) / 128);   // (8, 64)
    gemm_out<<<gg, 256, 0, stream>>>(AOb, wob, bo, (float*)d_out);
}